// Round 5
// baseline (1442.482 us; speedup 1.0000x reference)
//
#include <hip/hip_runtime.h>

#define B_   2
#define N_   16384
#define S_   4096
#define D1_  128
#define D2_  256
#define C1_  256
#define C2_  128
#define M_   (B_ * N_)   // 32768 rows

#define GMIN  (-4.0f)
#define INVH  (4.0f)
#define H_    (0.25f)
#define NC_   32          // cells per dim
#define NC3_  (NC_ * NC_ * NC_)

typedef __bf16 bf16_t;
typedef bf16_t bf16x8 __attribute__((ext_vector_type(8)));
typedef bf16_t bf16x4 __attribute__((ext_vector_type(4)));
typedef float  f32x4  __attribute__((ext_vector_type(4)));

// ---------------------------------------------------------------- helpers
__device__ __forceinline__ void gload16(const void* g, void* l) {
  __builtin_amdgcn_global_load_lds(
      (const __attribute__((address_space(1))) void*)g,
      (__attribute__((address_space(3))) void*)l, 16, 0, 0);
}

__device__ __forceinline__ float med3f(float a, float b, float c) {
  float d;
  asm("v_med3_f32 %0, %1, %2, %3" : "=v"(d) : "v"(a), "v"(b), "v"(c));
  return d;
}

__device__ __forceinline__ int cellof(float x) {
  int c = (int)floorf((x - GMIN) * INVH);
  return min(NC_ - 1, max(0, c));
}

// ---------------------------------------------------------------- K0: setup — transposes + weight prep + c4 + cell counts
__global__ __launch_bounds__(256) void setup_k(const float* __restrict__ points2,
                                               const float* __restrict__ points1,
                                               const float* __restrict__ w1,
                                               const float* __restrict__ w2,
                                               const float* __restrict__ xyz2,
                                               float* __restrict__ p2t,
                                               bf16_t* __restrict__ X,
                                               bf16_t* __restrict__ w1t,
                                               bf16_t* __restrict__ w2t,
                                               float4* __restrict__ c4,
                                               int* __restrict__ counts) {
  __shared__ float tile[32][33];
  int bi = blockIdx.x, t = threadIdx.x;
  int tx = t & 31, ty = t >> 5;
  if (bi < 2048) {
    int b = bi >> 10, rest = bi & 1023;
    int s0 = (rest & 127) * 32, c0 = (rest >> 7) * 32;
    const float* src = points2 + (size_t)b * D2_ * S_;
#pragma unroll
    for (int k = 0; k < 4; ++k)
      tile[ty + k * 8][tx] = src[(size_t)(c0 + ty + k * 8) * S_ + s0 + tx];
    __syncthreads();
    float* dst = p2t + (size_t)b * S_ * D2_;
#pragma unroll
    for (int k = 0; k < 4; ++k)
      dst[(size_t)(s0 + ty + k * 8) * D2_ + c0 + tx] = tile[tx][ty + k * 8];
  } else if (bi < 6144) {
    int bj = bi - 2048;
    int b = bj >> 11, rest = bj & 2047;
    int n0 = (rest & 511) * 32, c0 = (rest >> 9) * 32;
    const float* src = points1 + (size_t)b * D1_ * N_;
#pragma unroll
    for (int k = 0; k < 4; ++k)
      tile[ty + k * 8][tx] = src[(size_t)(c0 + ty + k * 8) * N_ + n0 + tx];
    __syncthreads();
#pragma unroll
    for (int k = 0; k < 4; ++k)
      X[(size_t)(b * N_ + n0 + ty + k * 8) * 384 + c0 + tx] = (bf16_t)tile[tx][ty + k * 8];
  } else {
    int i = (bi - 6144) * 256 + t;
    if (i < C1_ * 384) {                       // w1t[n][k] = w1[k][n]
      int n = i / 384, k = i % 384;
      w1t[i] = (bf16_t)w1[(size_t)k * C1_ + n];
    } else if (i < C1_ * 384 + C2_ * C1_) {
      int j = i - C1_ * 384;                   // w2t[n][k] = w2[k][n]
      int n = j / C1_, k = j % C1_;
      w2t[j] = (bf16_t)w2[(size_t)k * C2_ + n];
    } else {
      int j = i - (C1_ * 384 + C2_ * C1_);     // 0 .. B*S-1
      if (j < B_ * S_) {
        int b = j >> 12, s = j & (S_ - 1);
        const float* X2p = xyz2 + (size_t)b * 3 * S_;
        float x = X2p[s], y = X2p[S_ + s], z = X2p[2 * S_ + s];
        c4[j] = make_float4(-2.f * x, -2.f * y, -2.f * z, x * x + y * y + z * z);
        int cid = (cellof(x) << 10) | (cellof(y) << 5) | cellof(z);
        atomicAdd(&counts[b * NC3_ + cid], 1);
      }
    }
  }
}

// ---------------------------------------------------------------- K1: exclusive scan of cell counts (one block per batch)
__global__ __launch_bounds__(1024) void scan_k(const int* __restrict__ counts,
                                               int* __restrict__ starts,
                                               int* __restrict__ cursor) {
  __shared__ int ss[1024];
  int b = blockIdx.x, t = threadIdx.x;
  const int* cb = counts + b * NC3_;
  int* sb = starts + b * (NC3_ + 1);
  int* ub = cursor + b * NC3_;
  int base = t * 32;
  int c[32];
  int mysum = 0;
#pragma unroll
  for (int i = 0; i < 8; ++i) {
    int4 v = *(const int4*)(cb + base + i * 4);
    c[i * 4 + 0] = v.x; c[i * 4 + 1] = v.y; c[i * 4 + 2] = v.z; c[i * 4 + 3] = v.w;
    mysum += v.x + v.y + v.z + v.w;
  }
  ss[t] = mysum;
  __syncthreads();
  for (int o = 1; o < 1024; o <<= 1) {
    int v = (t >= o) ? ss[t - o] : 0;
    __syncthreads();
    ss[t] += v;
    __syncthreads();
  }
  int run = ss[t] - mysum;                 // exclusive prefix
#pragma unroll
  for (int i = 0; i < 32; ++i) {
    sb[base + i] = run;
    ub[base + i] = run;
    run += c[i];
  }
  if (t == 1023) sb[NC3_] = run;           // sentinel = 4096
}

// ---------------------------------------------------------------- K2: scatter candidates into cell-sorted order
__global__ __launch_bounds__(512) void scatter_k(const float4* __restrict__ c4,
                                                 int* __restrict__ cursor,
                                                 float4* __restrict__ c4s,
                                                 int* __restrict__ sidx) {
  int j = blockIdx.x * 512 + threadIdx.x;
  if (j >= B_ * S_) return;
  int b = j >> 12, s = j & (S_ - 1);
  float4 c = c4[j];
  float x = c.x * -0.5f, y = c.y * -0.5f, z = c.z * -0.5f;
  int cid = (cellof(x) << 10) | (cellof(y) << 5) | cellof(z);
  int pos = atomicAdd(&cursor[b * NC3_ + cid], 1);
  c4s[b * S_ + pos] = c;
  sidx[b * S_ + pos] = s;
}

// ---------------------------------------------------------------- K3: grid-pruned exact 3-NN + fused weighted gather
// 512 blocks x 512 threads; 64 queries/block, 8 lanes per query.
#define INSERT3(v, ix)                                                   \
  {                                                                      \
    bool b0 = (v) < m0, b1 = (v) < m1, b2 = (v) < m2;                    \
    float nm0 = fminf((v), m0);                                          \
    float nm1 = med3f(m0, (v), m1);                                      \
    float nm2 = med3f(m1, (v), m2);                                      \
    j2 = b1 ? j1 : (b2 ? (ix) : j2);                                     \
    j1 = b0 ? j0 : (b1 ? (ix) : j1);                                     \
    j0 = b0 ? (ix) : j0;                                                 \
    m0 = nm0; m1 = nm1; m2 = nm2;                                        \
  }

__global__ __launch_bounds__(512, 4) void knn2_k(const float* __restrict__ xyz1,
                                                 const float4* __restrict__ c4s,
                                                 const int* __restrict__ sidx,
                                                 const int* __restrict__ starts,
                                                 const float* __restrict__ p2t,
                                                 bf16_t* __restrict__ X) {
  const float FINF = __builtin_inff();
  int t = threadIdx.x;
  int sub = t & 7;
  int gq = blockIdx.x * 64 + (t >> 3);        // global query 0..32767
  int b  = gq >> 14, nn = gq & (N_ - 1);
  const float* X1 = xyz1 + (size_t)b * 3 * N_;
  float ax = X1[nn], ay = X1[N_ + nn], az = X1[2 * N_ + nn];
  float negp = -(ax * ax + ay * ay + az * az);
  float p = -negp;
  int cx = cellof(ax), cy = cellof(ay), cz = cellof(az);
  const float4* cb = c4s + (size_t)b * S_;
  const int*    ib = sidx + b * S_;
  const int*    sb = starts + b * (NC3_ + 1);
  float m0 = 3e38f, m1 = 3e38f, m2 = 3e38f;
  int   j0 = 0, j1 = 0, j2 = 0;
  for (int r = 0; r <= 31; ++r) {
    int cnt = 0;
    for (int ox = -r; ox <= r; ++ox) {
      for (int oy = -r; oy <= r; ++oy) {
        for (int oz = -r; oz <= r; ++oz) {
          // skip interior of the box (already scanned in earlier rings)
          if (r > 0) {
            int axo = ox < 0 ? -ox : ox, ayo = oy < 0 ? -oy : oy, azo = oz < 0 ? -oz : oz;
            int mx = max(axo, max(ayo, azo));
            if (mx < r) { oz = r - 1; continue; }
          }
          int gx = cx + ox, gy = cy + oy, gz = cz + oz;
          bool inb = ((unsigned)gx < NC_) && ((unsigned)gy < NC_) && ((unsigned)gz < NC_);
          bool mine = ((cnt & 7) == sub);
          ++cnt;
          if (!(inb && mine)) continue;
          int cid = (gx << 10) | (gy << 5) | gz;
          int s0 = sb[cid], s1 = sb[cid + 1];
          for (int k = s0; k < s1; ++k) {
            float4 c = cb[k];
            int idx = ib[k];
            float v = c.w;
            v = fmaf(az, c.z, v);
            v = fmaf(ay, c.y, v);
            v = fmaf(ax, c.x, v);
            v = fmaxf(v, negp);
            INSERT3(v, idx);
          }
        }
      }
    }
    // conservative bound: closest possible unscanned point
    float bxu = (cx + r + 1 <= NC_ - 1) ? (GMIN + (float)(cx + r + 1) * H_ - ax) : FINF;
    float bxl = (cx - r >= 1)           ? (ax - (GMIN + (float)(cx - r) * H_)) : FINF;
    float byu = (cy + r + 1 <= NC_ - 1) ? (GMIN + (float)(cy + r + 1) * H_ - ay) : FINF;
    float byl = (cy - r >= 1)           ? (ay - (GMIN + (float)(cy - r) * H_)) : FINF;
    float bzu = (cz + r + 1 <= NC_ - 1) ? (GMIN + (float)(cz + r + 1) * H_ - az) : FINF;
    float bzl = (cz - r >= 1)           ? (az - (GMIN + (float)(cz - r) * H_)) : FINF;
    float gap = fminf(fminf(fminf(bxu, bxl), fminf(byu, byl)), fminf(bzu, bzl));
    gap = fmaxf(gap, 0.f);
    float bound2 = gap * gap;
    float m2g = m2;
    m2g = fminf(m2g, __shfl_xor(m2g, 1));
    m2g = fminf(m2g, __shfl_xor(m2g, 2));
    m2g = fminf(m2g, __shfl_xor(m2g, 4));
    if (p + m2g <= bound2) break;
  }
  // butterfly merge of the 8 lanes' top-3 lists
#pragma unroll
  for (int st = 1; st <= 4; st <<= 1) {
    float om0 = __shfl_xor(m0, st), om1 = __shfl_xor(m1, st), om2 = __shfl_xor(m2, st);
    int   oj0 = __shfl_xor(j0, st), oj1 = __shfl_xor(j1, st), oj2 = __shfl_xor(j2, st);
    INSERT3(om0, oj0);
    INSERT3(om1, oj1);
    INSERT3(om2, oj2);
  }
  float d0 = fmaxf(p + m0, 1e-6f);
  float d1 = fmaxf(p + m1, 1e-6f);
  float d2 = fmaxf(p + m2, 1e-6f);
  float r0 = 1.f / d0, r1 = 1.f / d1, r2 = 1.f / d2;
  float dn = fmaxf(r0 + r1 + r2, 1e-6f);
  float w0 = r0 / dn, w1 = r1 / dn, w2 = r2 / dn;
  // fused gather: this lane handles 32 channels
  int s32 = sub * 32;
  const float* pb = p2t + (size_t)b * S_ * D2_;
  const float4* A4 = (const float4*)(pb + (size_t)j0 * D2_ + s32);
  const float4* B4 = (const float4*)(pb + (size_t)j1 * D2_ + s32);
  const float4* C4p = (const float4*)(pb + (size_t)j2 * D2_ + s32);
  bf16_t* xo = X + (size_t)gq * 384 + 128 + s32;
#pragma unroll
  for (int u = 0; u < 8; ++u) {
    float4 A = A4[u], Bv = B4[u], Cv = C4p[u];
    bf16x4 o;
    o[0] = (bf16_t)(w0 * A.x + w1 * Bv.x + w2 * Cv.x);
    o[1] = (bf16_t)(w0 * A.y + w1 * Bv.y + w2 * Cv.y);
    o[2] = (bf16_t)(w0 * A.z + w1 * Bv.z + w2 * Cv.z);
    o[3] = (bf16_t)(w0 * A.w + w1 * Bv.w + w2 * Cv.w);
    *(bf16x4*)&xo[u * 4] = o;
  }
}

// ---------------------------------------------------------------- K4: GEMM1 [32768x384]@[384x256] + b1 -> y1 bf16, fused BN stats
__global__ __launch_bounds__(256) void gemm1_k(const bf16_t* __restrict__ A,
                                               const bf16_t* __restrict__ Bt,
                                               const float* __restrict__ bias,
                                               bf16_t* __restrict__ Y,
                                               float* __restrict__ st) {
  const int K = 384;
  __shared__ bf16_t As[128 * 32];
  __shared__ bf16_t Bs[128 * 32];
  int tid = threadIdx.x, lane = tid & 63, w = tid >> 6;
  int wr = w >> 1, wc = w & 1;
  int m0 = blockIdx.x * 128, n0 = blockIdx.y * 128;
  int e0 = (w * 2 + 0) * 512 + lane * 8;
  int e1 = (w * 2 + 1) * 512 + lane * 8;
  int ra0 = e0 >> 5, ca0 = e0 & 31;
  int ra1 = e1 >> 5, ca1 = e1 & 31;
  f32x4 acc[4][4];
  f32x4 z = {0.f, 0.f, 0.f, 0.f};
#pragma unroll
  for (int i = 0; i < 4; ++i)
#pragma unroll
    for (int j = 0; j < 4; ++j) acc[i][j] = z;
  for (int k0 = 0; k0 < K; k0 += 32) {
    __syncthreads();
    gload16(A + (size_t)(m0 + ra0) * K + k0 + ca0, &As[e0]);
    gload16(A + (size_t)(m0 + ra1) * K + k0 + ca1, &As[e1]);
    gload16(Bt + (size_t)(n0 + ra0) * K + k0 + ca0, &Bs[e0]);
    gload16(Bt + (size_t)(n0 + ra1) * K + k0 + ca1, &Bs[e1]);
    __syncthreads();
    bf16x8 af[4], bfr[4];
    int arow = wr * 64 + (lane & 15);
    int brow = wc * 64 + (lane & 15);
    int kc = 8 * (lane >> 4);
#pragma unroll
    for (int i = 0; i < 4; ++i) af[i]  = *(const bf16x8*)&As[(arow + i * 16) * 32 + kc];
#pragma unroll
    for (int j = 0; j < 4; ++j) bfr[j] = *(const bf16x8*)&Bs[(brow + j * 16) * 32 + kc];
#pragma unroll
    for (int i = 0; i < 4; ++i)
#pragma unroll
      for (int j = 0; j < 4; ++j)
        acc[i][j] = __builtin_amdgcn_mfma_f32_16x16x32_bf16(af[i], bfr[j], acc[i][j], 0, 0, 0);
  }
#pragma unroll
  for (int j = 0; j < 4; ++j) {
    int col = n0 + wc * 64 + j * 16 + (lane & 15);
    float bv = bias[col];
    float sj = 0.f, ssj = 0.f;
#pragma unroll
    for (int i = 0; i < 4; ++i) {
      int r = m0 + wr * 64 + i * 16 + ((lane >> 4) << 2);
#pragma unroll
      for (int q = 0; q < 4; ++q) {
        float y = acc[i][j][q] + bv;
        Y[(size_t)(r + q) * C1_ + col] = (bf16_t)y;
        sj += y; ssj += y * y;
      }
    }
    sj  += __shfl_xor(sj, 16);  sj  += __shfl_xor(sj, 32);
    ssj += __shfl_xor(ssj, 16); ssj += __shfl_xor(ssj, 32);
    if ((lane >> 4) == 0) {
      atomicAdd(&st[col], sj);
      atomicAdd(&st[C1_ + col], ssj);
    }
  }
}

// ---------------------------------------------------------------- K5: x2 = relu(a*y1+s) bf16 (BN finalize folded in)
__global__ __launch_bounds__(256) void bn1apply_k(const bf16_t* __restrict__ Y,
                                                  const float* __restrict__ st,
                                                  const float* __restrict__ g,
                                                  const float* __restrict__ be,
                                                  bf16_t* __restrict__ X2) {
  __shared__ float sa[256], sb[256];
  int t = threadIdx.x;
  {
    const float invM = 1.f / (float)M_;
    float mu  = st[t] * invM;
    float var = fmaxf(st[C1_ + t] * invM - mu * mu, 0.f);
    float a = g[t] * rsqrtf(var + 1e-5f);
    sa[t] = a;
    sb[t] = be[t] - mu * a;
  }
  __syncthreads();
  int cc = (t & 31) * 8;
  float a[8], s[8];
#pragma unroll
  for (int u = 0; u < 8; ++u) { a[u] = sa[cc + u]; s[u] = sb[cc + u]; }
  int r0 = blockIdx.x * 64 + (t >> 5);
  for (int it = 0; it < 8; ++it) {
    int r = r0 + it * 8;
    bf16x8 v = *(const bf16x8*)&Y[(size_t)r * C1_ + cc];
    bf16x8 o;
#pragma unroll
    for (int u = 0; u < 8; ++u) {
      float f = (float)v[u];
      f = fmaxf(a[u] * f + s[u], 0.f);
      o[u] = (bf16_t)f;
    }
    *(bf16x8*)&X2[(size_t)r * C1_ + cc] = o;
  }
}

// ---------------------------------------------------------------- K6: GEMM2 [32768x256]@[256x128] + b2 -> raw y2 transposed into d_out, fused BN stats
__global__ __launch_bounds__(256) void gemm2_k(const bf16_t* __restrict__ A,
                                               const bf16_t* __restrict__ Bt,
                                               const float* __restrict__ bias,
                                               float* __restrict__ OUT,
                                               float* __restrict__ st) {
  const int K = 256;
  __shared__ bf16_t As[128 * 32];
  __shared__ bf16_t Bs[128 * 32];
  int tid = threadIdx.x, lane = tid & 63, w = tid >> 6;
  int wr = w >> 1, wc = w & 1;
  int m0 = blockIdx.x * 128;
  int e0 = (w * 2 + 0) * 512 + lane * 8;
  int e1 = (w * 2 + 1) * 512 + lane * 8;
  int ra0 = e0 >> 5, ca0 = e0 & 31;
  int ra1 = e1 >> 5, ca1 = e1 & 31;
  f32x4 acc[4][4];
  f32x4 z = {0.f, 0.f, 0.f, 0.f};
#pragma unroll
  for (int i = 0; i < 4; ++i)
#pragma unroll
    for (int j = 0; j < 4; ++j) acc[i][j] = z;
  for (int k0 = 0; k0 < K; k0 += 32) {
    __syncthreads();
    gload16(A + (size_t)(m0 + ra0) * K + k0 + ca0, &As[e0]);
    gload16(A + (size_t)(m0 + ra1) * K + k0 + ca1, &As[e1]);
    gload16(Bt + (size_t)ra0 * K + k0 + ca0, &Bs[e0]);
    gload16(Bt + (size_t)ra1 * K + k0 + ca1, &Bs[e1]);
    __syncthreads();
    bf16x8 af[4], bfr[4];
    int arow = wr * 64 + (lane & 15);
    int brow = wc * 64 + (lane & 15);
    int kc = 8 * (lane >> 4);
#pragma unroll
    for (int i = 0; i < 4; ++i) af[i]  = *(const bf16x8*)&As[(arow + i * 16) * 32 + kc];
#pragma unroll
    for (int j = 0; j < 4; ++j) bfr[j] = *(const bf16x8*)&Bs[(brow + j * 16) * 32 + kc];
#pragma unroll
    for (int i = 0; i < 4; ++i)
#pragma unroll
      for (int j = 0; j < 4; ++j)
        acc[i][j] = __builtin_amdgcn_mfma_f32_16x16x32_bf16(af[i], bfr[j], acc[i][j], 0, 0, 0);
  }
#pragma unroll
  for (int j = 0; j < 4; ++j) {
    int col = wc * 64 + j * 16 + (lane & 15);
    float bv = bias[col];
    float sj = 0.f, ssj = 0.f;
#pragma unroll
    for (int i = 0; i < 4; ++i) {
      int r  = m0 + wr * 64 + i * 16 + ((lane >> 4) << 2);
      int bb = r >> 14, n = r & (N_ - 1);
      f32x4 v = acc[i][j];
#pragma unroll
      for (int q = 0; q < 4; ++q) {
        v[q] += bv;
        sj += v[q]; ssj += v[q] * v[q];
      }
      *(f32x4*)&OUT[((size_t)(bb * C2_ + col)) * N_ + n] = v;
    }
    sj  += __shfl_xor(sj, 16);  sj  += __shfl_xor(sj, 32);
    ssj += __shfl_xor(ssj, 16); ssj += __shfl_xor(ssj, 32);
    if ((lane >> 4) == 0) {
      atomicAdd(&st[col], sj);
      atomicAdd(&st[C2_ + col], ssj);
    }
  }
}

// ---------------------------------------------------------------- K7: in-place BN2+ReLU on d_out (BN finalize folded in)
__global__ __launch_bounds__(256) void bn2apply_k(float* __restrict__ OUT,
                                                  const float* __restrict__ st,
                                                  const float* __restrict__ g,
                                                  const float* __restrict__ be) {
  __shared__ float ab[2];
  int t = threadIdx.x;
  int c = (blockIdx.x >> 4) & 127;             // 16 blocks per (b,c) row
  if (t == 0) {
    const float invM = 1.f / (float)M_;
    float mu  = st[c] * invM;
    float var = fmaxf(st[C2_ + c] * invM - mu * mu, 0.f);
    float a = g[c] * rsqrtf(var + 1e-5f);
    ab[0] = a;
    ab[1] = be[c] - mu * a;
  }
  __syncthreads();
  float a = ab[0], s = ab[1];
  size_t i4 = (size_t)blockIdx.x * 256 + t;    // float4 index
  f32x4 v = *(f32x4*)&OUT[i4 * 4];
#pragma unroll
  for (int u = 0; u < 4; ++u) v[u] = fmaxf(a * v[u] + s, 0.f);
  *(f32x4*)&OUT[i4 * 4] = v;
}

// ---------------------------------------------------------------- launch
extern "C" void kernel_launch(void* const* d_in, const int* in_sizes, int n_in,
                              void* d_out, int out_size, void* d_ws, size_t ws_size,
                              hipStream_t stream) {
  const float* xyz1    = (const float*)d_in[0];
  const float* xyz2    = (const float*)d_in[1];
  const float* points1 = (const float*)d_in[2];
  const float* points2 = (const float*)d_in[3];
  const float* w1      = (const float*)d_in[4];
  const float* b1      = (const float*)d_in[5];
  const float* g1      = (const float*)d_in[6];
  const float* beta1   = (const float*)d_in[7];
  const float* w2      = (const float*)d_in[8];
  const float* b2      = (const float*)d_in[9];
  const float* g2      = (const float*)d_in[10];
  const float* beta2   = (const float*)d_in[11];
  float* out = (float*)d_out;

  char* p = (char*)d_ws;
  size_t off = 0;
  bf16_t* w1t = (bf16_t*)(p + off); off += (size_t)C1_ * 384 * 2;      // 196608
  bf16_t* w2t = (bf16_t*)(p + off); off += (size_t)C2_ * C1_ * 2;      // 65536
  float*  p2t = (float*)(p + off);  off += (size_t)B_ * S_ * D2_ * 4;  // 8388608
  bf16_t* X   = (bf16_t*)(p + off); off += (size_t)M_ * 384 * 2;       // 25165824
  bf16_t* Y1  = (bf16_t*)(p + off); off += (size_t)M_ * C1_ * 2;       // 16777216
  bf16_t* X2  = (bf16_t*)(p + off); off += (size_t)M_ * C1_ * 2;       // 16777216
  float4* C4  = (float4*)(p + off); off += (size_t)B_ * S_ * 16;       // 131072
  float4* C4S = (float4*)(p + off); off += (size_t)B_ * S_ * 16;       // 131072
  int*    SIDX = (int*)(p + off);   off += (size_t)B_ * S_ * 4;        // 32768
  int*    CNTS = (int*)(p + off);   off += (size_t)B_ * NC3_ * 4;      // 262144
  int*    STRT = (int*)(p + off);   off += ((size_t)B_ * (NC3_ + 1) * 4 + 15) & ~15ull;
  int*    CURS = (int*)(p + off);   off += (size_t)B_ * NC3_ * 4;      // 262144
  float*  ST1 = (float*)(p + off);  off += 2048;                       // 256 sum + 256 ss
  float*  ST2 = (float*)(p + off);  off += 1024;                       // 128 sum + 128 ss

  hipMemsetAsync(ST1, 0, 3072, stream);               // ST1 + ST2 contiguous
  hipMemsetAsync(CNTS, 0, B_ * NC3_ * 4, stream);

  setup_k<<<6688, 256, 0, stream>>>(points2, points1, w1, w2, xyz2, p2t, X, w1t, w2t, C4, CNTS);
  scan_k<<<2, 1024, 0, stream>>>(CNTS, STRT, CURS);
  scatter_k<<<16, 512, 0, stream>>>(C4, CURS, C4S, SIDX);
  knn2_k<<<512, 512, 0, stream>>>(xyz1, C4S, SIDX, STRT, p2t, X);
  gemm1_k<<<dim3(M_ / 128, 2), 256, 0, stream>>>(X, w1t, b1, Y1, ST1);
  bn1apply_k<<<512, 256, 0, stream>>>(Y1, ST1, g1, beta1, X2);
  gemm2_k<<<M_ / 128, 256, 0, stream>>>(X2, w2t, b2, out, ST2);
  bn2apply_k<<<4096, 256, 0, stream>>>(out, ST2, g2, beta2);
}

// Round 6
// 226.400 us; speedup vs baseline: 6.3714x; 6.3714x over previous
//
#include <hip/hip_runtime.h>

#define B_   2
#define N_   16384
#define S_   4096
#define D1_  128
#define D2_  256
#define C1_  256
#define C2_  128
#define M_   (B_ * N_)   // 32768 rows

#define GMIN  (-4.0f)
#define BINS_ 128
#define BH_   (0.0625f)
#define BINV_ (16.0f)

typedef __bf16 bf16_t;
typedef bf16_t bf16x8 __attribute__((ext_vector_type(8)));
typedef bf16_t bf16x4 __attribute__((ext_vector_type(4)));
typedef float  f32x4  __attribute__((ext_vector_type(4)));

// ---------------------------------------------------------------- helpers
__device__ __forceinline__ void gload16(const void* g, void* l) {
  __builtin_amdgcn_global_load_lds(
      (const __attribute__((address_space(1))) void*)g,
      (__attribute__((address_space(3))) void*)l, 16, 0, 0);
}

__device__ __forceinline__ float med3f(float a, float b, float c) {
  float d;
  asm("v_med3_f32 %0, %1, %2, %3" : "=v"(d) : "v"(a), "v"(b), "v"(c));
  return d;
}

__device__ __forceinline__ int binof(float x) {
  int c = (int)floorf((x - GMIN) * BINV_);
  return min(BINS_ - 1, max(0, c));
}

// ---------------------------------------------------------------- K0: setup
// blocks [0,2048): points2 transpose -> p2t [B][4096][256]
// blocks [2048,6144): points1 transpose -> X[r][0:128) bf16 (row stride 384)
// blocks [6144,6688): w1t/w2t bf16 + c4 (-2x,-2y,-2z,|c|^2) + candidate x-bin counts
// blocks [6688,6720): query x-bin counts (LDS hist)
__global__ __launch_bounds__(256) void setup_k(const float* __restrict__ points2,
                                               const float* __restrict__ points1,
                                               const float* __restrict__ w1,
                                               const float* __restrict__ w2,
                                               const float* __restrict__ xyz2,
                                               const float* __restrict__ xyz1,
                                               float* __restrict__ p2t,
                                               bf16_t* __restrict__ X,
                                               bf16_t* __restrict__ w1t,
                                               bf16_t* __restrict__ w2t,
                                               float4* __restrict__ c4,
                                               int* __restrict__ ccnt,
                                               int* __restrict__ qcnt) {
  __shared__ float tile[32][33];
  __shared__ int hist[BINS_];
  int bi = blockIdx.x, t = threadIdx.x;
  int tx = t & 31, ty = t >> 5;
  if (bi < 2048) {
    int b = bi >> 10, rest = bi & 1023;
    int s0 = (rest & 127) * 32, c0 = (rest >> 7) * 32;
    const float* src = points2 + (size_t)b * D2_ * S_;
#pragma unroll
    for (int k = 0; k < 4; ++k)
      tile[ty + k * 8][tx] = src[(size_t)(c0 + ty + k * 8) * S_ + s0 + tx];
    __syncthreads();
    float* dst = p2t + (size_t)b * S_ * D2_;
#pragma unroll
    for (int k = 0; k < 4; ++k)
      dst[(size_t)(s0 + ty + k * 8) * D2_ + c0 + tx] = tile[tx][ty + k * 8];
  } else if (bi < 6144) {
    int bj = bi - 2048;
    int b = bj >> 11, rest = bj & 2047;
    int n0 = (rest & 511) * 32, c0 = (rest >> 9) * 32;
    const float* src = points1 + (size_t)b * D1_ * N_;
#pragma unroll
    for (int k = 0; k < 4; ++k)
      tile[ty + k * 8][tx] = src[(size_t)(c0 + ty + k * 8) * N_ + n0 + tx];
    __syncthreads();
#pragma unroll
    for (int k = 0; k < 4; ++k)
      X[(size_t)(b * N_ + n0 + ty + k * 8) * 384 + c0 + tx] = (bf16_t)tile[tx][ty + k * 8];
  } else if (bi < 6688) {
    int i = (bi - 6144) * 256 + t;
    if (i < C1_ * 384) {                       // w1t[n][k] = w1[k][n]
      int n = i / 384, k = i % 384;
      w1t[i] = (bf16_t)w1[(size_t)k * C1_ + n];
    } else if (i < C1_ * 384 + C2_ * C1_) {
      int j = i - C1_ * 384;                   // w2t[n][k] = w2[k][n]
      int n = j / C1_, k = j % C1_;
      w2t[j] = (bf16_t)w2[(size_t)k * C2_ + n];
    } else {
      int j = i - (C1_ * 384 + C2_ * C1_);     // 0 .. B*S-1
      int b = j >> 12, s = j & (S_ - 1);
      const float* X2p = xyz2 + (size_t)b * 3 * S_;
      float x = X2p[s], y = X2p[S_ + s], z = X2p[2 * S_ + s];
      c4[j] = make_float4(-2.f * x, -2.f * y, -2.f * z, x * x + y * y + z * z);
      atomicAdd(&ccnt[b * BINS_ + binof(x)], 1);
    }
  } else {
    int gq0 = (bi - 6688) * 1024;              // 1024 queries per block
    int b = gq0 >> 14;
    if (t < BINS_) hist[t] = 0;
    __syncthreads();
    const float* X1 = xyz1 + (size_t)b * 3 * N_;
#pragma unroll
    for (int u = 0; u < 4; ++u) {
      int n = (gq0 & (N_ - 1)) + t + u * 256;
      atomicAdd(&hist[binof(X1[n])], 1);
    }
    __syncthreads();
    if (t < BINS_) atomicAdd(&qcnt[b * BINS_ + t], hist[t]);
  }
}

// ---------------------------------------------------------------- K1: exclusive scans (4 arrays of 128)
__global__ __launch_bounds__(256) void scan2_k(const int* __restrict__ ccnt,
                                               const int* __restrict__ qcnt,
                                               int* __restrict__ cstart,
                                               int* __restrict__ qstart,
                                               int* __restrict__ ccur,
                                               int* __restrict__ qcur) {
  __shared__ int ss[4][64];
  int t = threadIdx.x, wv = t >> 6, l = t & 63;
  const int* cnt = (wv < 2) ? (ccnt + wv * BINS_) : (qcnt + (wv - 2) * BINS_);
  int* st = (wv < 2) ? (cstart + wv * (BINS_ + 1)) : (qstart + (wv - 2) * (BINS_ + 1));
  int* cu = (wv < 2) ? (ccur + wv * BINS_) : (qcur + (wv - 2) * BINS_);
  int c0 = cnt[l * 2], c1 = cnt[l * 2 + 1];
  int sum = c0 + c1;
  ss[wv][l] = sum;
  __syncthreads();
  int acc = 0;
  for (int i = 0; i < l; ++i) acc += ss[wv][i];
  st[l * 2] = acc;         cu[l * 2] = acc;
  st[l * 2 + 1] = acc + c0; cu[l * 2 + 1] = acc + c0;
  if (l == 63) st[BINS_] = acc + sum;
}

// ---------------------------------------------------------------- K2: scatter candidates by x-bin
__global__ __launch_bounds__(512) void scatterc_k(const float4* __restrict__ c4,
                                                  int* __restrict__ ccur,
                                                  float4* __restrict__ c4s,
                                                  int* __restrict__ sidx) {
  int j = blockIdx.x * 512 + threadIdx.x;
  if (j >= B_ * S_) return;
  int b = j >> 12, s = j & (S_ - 1);
  float4 c = c4[j];
  int bin = binof(c.x * -0.5f);
  int pos = atomicAdd(&ccur[b * BINS_ + bin], 1);
  c4s[b * S_ + pos] = c;
  sidx[b * S_ + pos] = s;
}

// ---------------------------------------------------------------- K3: scatter queries by x-bin
__global__ __launch_bounds__(512) void scatterq_k(const float* __restrict__ xyz1,
                                                  int* __restrict__ qcur,
                                                  float4* __restrict__ q4s,
                                                  int* __restrict__ qid) {
  int gq = blockIdx.x * 512 + threadIdx.x;
  if (gq >= M_) return;
  int b = gq >> 14, n = gq & (N_ - 1);
  const float* X1 = xyz1 + (size_t)b * 3 * N_;
  float ax = X1[n], ay = X1[N_ + n], az = X1[2 * N_ + n];
  float p = ax * ax + ay * ay + az * az;
  int bin = binof(ax);
  int pos = atomicAdd(&qcur[b * BINS_ + bin], 1);
  q4s[b * N_ + pos] = make_float4(ax, ay, az, p);
  qid[b * N_ + pos] = n;
}

// ---------------------------------------------------------------- K4: 1-D pruned exact 3-NN + fused weighted gather
#define INSERT3(v, ix)                                                   \
  {                                                                      \
    bool b0 = (v) < m0, b1 = (v) < m1, b2 = (v) < m2;                    \
    float nm0 = fminf((v), m0);                                          \
    float nm1 = med3f(m0, (v), m1);                                      \
    float nm2 = med3f(m1, (v), m2);                                      \
    j2 = b1 ? j1 : (b2 ? (ix) : j2);                                     \
    j1 = b0 ? j0 : (b1 ? (ix) : j1);                                     \
    j0 = b0 ? (ix) : j0;                                                 \
    m0 = nm0; m1 = nm1; m2 = nm2;                                        \
  }

#define SCANBIN(nb)                                                      \
  {                                                                      \
    int s0 = sb[nb], s1 = sb[(nb) + 1];                                  \
    for (int k = s0 + cslot; k < s1; k += 16) {                          \
      float4 c = cb[k];                                                  \
      int idx = ib[k];                                                   \
      float v = c.w;                                                     \
      v = fmaf(az, c.z, v);                                              \
      v = fmaf(ay, c.y, v);                                              \
      v = fmaf(ax, c.x, v);                                              \
      v = fmaxf(v, negp);                                                \
      INSERT3(v, idx);                                                   \
    }                                                                    \
  }

// 1024 blocks x 512 threads (8 waves). Wave: 4 sorted queries x 16 lanes.
__global__ __launch_bounds__(512, 8) void knn3_k(const float4* __restrict__ q4s,
                                                 const int* __restrict__ qid,
                                                 const float4* __restrict__ c4s,
                                                 const int* __restrict__ sidx,
                                                 const int* __restrict__ cstart,
                                                 const float* __restrict__ p2t,
                                                 bf16_t* __restrict__ X) {
  int t = threadIdx.x, wv = t >> 6, l = t & 63;
  int grp = l >> 4, cslot = l & 15;
  int b = blockIdx.x >> 9;                      // 512 blocks per batch
  int spos = (blockIdx.x & 511) * 32 + wv * 4 + grp;
  float4 q = q4s[(size_t)b * N_ + spos];
  int qidx = qid[(size_t)b * N_ + spos];
  float ax = q.x, ay = q.y, az = q.z, p = q.w;
  float negp = -p;
  const float4* cb = c4s + (size_t)b * S_;
  const int*    ib = sidx + b * S_;
  const int*    sb = cstart + b * (BINS_ + 1);
  float m0 = 3e38f, m1 = 3e38f, m2 = 3e38f;
  int   j0 = 0, j1 = 0, j2 = 0;
  float rax = __int_as_float(__builtin_amdgcn_readfirstlane(__float_as_int(ax)));
  int qb = binof(rax);
  int blo = qb, bhi = qb;
  SCANBIN(qb);
  while (1) {
    float U = m2;
    U = fminf(U, __shfl_xor(U, 1));
    U = fminf(U, __shfl_xor(U, 2));
    U = fminf(U, __shfl_xor(U, 4));
    U = fminf(U, __shfl_xor(U, 8));
    float gl = (blo > 0)         ? ax - (GMIN + (float)blo * BH_) : 1e30f;
    float gr = (bhi < BINS_ - 1) ? (GMIN + (float)(bhi + 1) * BH_) - ax : 1e30f;
    float gap = fmaxf(fminf(gl, gr), 0.f);
    if (__all((p + U) <= gap * gap)) break;
    if (blo == 0 && bhi == BINS_ - 1) break;
    float gLr = (blo > 0)         ? rax - (GMIN + (float)blo * BH_) : 1e30f;
    float gRr = (bhi < BINS_ - 1) ? (GMIN + (float)(bhi + 1) * BH_) - rax : 1e30f;
    int nb;
    if (gLr <= gRr) nb = --blo; else nb = ++bhi;
    SCANBIN(nb);
  }
  // butterfly merge of the 16 lanes' top-3 lists
#pragma unroll
  for (int st = 1; st <= 8; st <<= 1) {
    float om0 = __shfl_xor(m0, st), om1 = __shfl_xor(m1, st), om2 = __shfl_xor(m2, st);
    int   oj0 = __shfl_xor(j0, st), oj1 = __shfl_xor(j1, st), oj2 = __shfl_xor(j2, st);
    INSERT3(om0, oj0);
    INSERT3(om1, oj1);
    INSERT3(om2, oj2);
  }
  float d0 = fmaxf(p + m0, 1e-6f);
  float d1 = fmaxf(p + m1, 1e-6f);
  float d2 = fmaxf(p + m2, 1e-6f);
  float r0 = 1.f / d0, r1 = 1.f / d1, r2 = 1.f / d2;
  float dn = fmaxf(r0 + r1 + r2, 1e-6f);
  float w0 = r0 / dn, w1 = r1 / dn, w2 = r2 / dn;
  // fused gather: 16 channels per lane
  int c0ch = cslot * 16;
  const float* pb = p2t + (size_t)b * S_ * D2_;
  const float4* A4 = (const float4*)(pb + (size_t)j0 * D2_ + c0ch);
  const float4* B4 = (const float4*)(pb + (size_t)j1 * D2_ + c0ch);
  const float4* C4p = (const float4*)(pb + (size_t)j2 * D2_ + c0ch);
  bf16_t* xo = X + ((size_t)(b * N_ + qidx)) * 384 + 128 + c0ch;
#pragma unroll
  for (int u = 0; u < 4; ++u) {
    float4 A = A4[u], Bv = B4[u], Cv = C4p[u];
    bf16x4 o;
    o[0] = (bf16_t)(w0 * A.x + w1 * Bv.x + w2 * Cv.x);
    o[1] = (bf16_t)(w0 * A.y + w1 * Bv.y + w2 * Cv.y);
    o[2] = (bf16_t)(w0 * A.z + w1 * Bv.z + w2 * Cv.z);
    o[3] = (bf16_t)(w0 * A.w + w1 * Bv.w + w2 * Cv.w);
    *(bf16x4*)&xo[u * 4] = o;
  }
}

// ---------------------------------------------------------------- K5: GEMM1 [32768x384]@[384x256] + b1 -> y1 bf16, fused BN stats
__global__ __launch_bounds__(256) void gemm1_k(const bf16_t* __restrict__ A,
                                               const bf16_t* __restrict__ Bt,
                                               const float* __restrict__ bias,
                                               bf16_t* __restrict__ Y,
                                               float* __restrict__ st) {
  const int K = 384;
  __shared__ bf16_t As[128 * 32];
  __shared__ bf16_t Bs[128 * 32];
  int tid = threadIdx.x, lane = tid & 63, w = tid >> 6;
  int wr = w >> 1, wc = w & 1;
  int m0 = blockIdx.x * 128, n0 = blockIdx.y * 128;
  int e0 = (w * 2 + 0) * 512 + lane * 8;
  int e1 = (w * 2 + 1) * 512 + lane * 8;
  int ra0 = e0 >> 5, ca0 = e0 & 31;
  int ra1 = e1 >> 5, ca1 = e1 & 31;
  f32x4 acc[4][4];
  f32x4 z = {0.f, 0.f, 0.f, 0.f};
#pragma unroll
  for (int i = 0; i < 4; ++i)
#pragma unroll
    for (int j = 0; j < 4; ++j) acc[i][j] = z;
  for (int k0 = 0; k0 < K; k0 += 32) {
    __syncthreads();
    gload16(A + (size_t)(m0 + ra0) * K + k0 + ca0, &As[e0]);
    gload16(A + (size_t)(m0 + ra1) * K + k0 + ca1, &As[e1]);
    gload16(Bt + (size_t)(n0 + ra0) * K + k0 + ca0, &Bs[e0]);
    gload16(Bt + (size_t)(n0 + ra1) * K + k0 + ca1, &Bs[e1]);
    __syncthreads();
    bf16x8 af[4], bfr[4];
    int arow = wr * 64 + (lane & 15);
    int brow = wc * 64 + (lane & 15);
    int kc = 8 * (lane >> 4);
#pragma unroll
    for (int i = 0; i < 4; ++i) af[i]  = *(const bf16x8*)&As[(arow + i * 16) * 32 + kc];
#pragma unroll
    for (int j = 0; j < 4; ++j) bfr[j] = *(const bf16x8*)&Bs[(brow + j * 16) * 32 + kc];
#pragma unroll
    for (int i = 0; i < 4; ++i)
#pragma unroll
      for (int j = 0; j < 4; ++j)
        acc[i][j] = __builtin_amdgcn_mfma_f32_16x16x32_bf16(af[i], bfr[j], acc[i][j], 0, 0, 0);
  }
#pragma unroll
  for (int j = 0; j < 4; ++j) {
    int col = n0 + wc * 64 + j * 16 + (lane & 15);
    float bv = bias[col];
    float sj = 0.f, ssj = 0.f;
#pragma unroll
    for (int i = 0; i < 4; ++i) {
      int r = m0 + wr * 64 + i * 16 + ((lane >> 4) << 2);
#pragma unroll
      for (int q = 0; q < 4; ++q) {
        float y = acc[i][j][q] + bv;
        Y[(size_t)(r + q) * C1_ + col] = (bf16_t)y;
        sj += y; ssj += y * y;
      }
    }
    sj  += __shfl_xor(sj, 16);  sj  += __shfl_xor(sj, 32);
    ssj += __shfl_xor(ssj, 16); ssj += __shfl_xor(ssj, 32);
    if ((lane >> 4) == 0) {
      atomicAdd(&st[col], sj);
      atomicAdd(&st[C1_ + col], ssj);
    }
  }
}

// ---------------------------------------------------------------- K6: x2 = relu(a*y1+s) bf16 (BN finalize folded in)
__global__ __launch_bounds__(256) void bn1apply_k(const bf16_t* __restrict__ Y,
                                                  const float* __restrict__ st,
                                                  const float* __restrict__ g,
                                                  const float* __restrict__ be,
                                                  bf16_t* __restrict__ X2) {
  __shared__ float sa[256], sb[256];
  int t = threadIdx.x;
  {
    const float invM = 1.f / (float)M_;
    float mu  = st[t] * invM;
    float var = fmaxf(st[C1_ + t] * invM - mu * mu, 0.f);
    float a = g[t] * rsqrtf(var + 1e-5f);
    sa[t] = a;
    sb[t] = be[t] - mu * a;
  }
  __syncthreads();
  int cc = (t & 31) * 8;
  float a[8], s[8];
#pragma unroll
  for (int u = 0; u < 8; ++u) { a[u] = sa[cc + u]; s[u] = sb[cc + u]; }
  int r0 = blockIdx.x * 64 + (t >> 5);
  for (int it = 0; it < 8; ++it) {
    int r = r0 + it * 8;
    bf16x8 v = *(const bf16x8*)&Y[(size_t)r * C1_ + cc];
    bf16x8 o;
#pragma unroll
    for (int u = 0; u < 8; ++u) {
      float f = (float)v[u];
      f = fmaxf(a[u] * f + s[u], 0.f);
      o[u] = (bf16_t)f;
    }
    *(bf16x8*)&X2[(size_t)r * C1_ + cc] = o;
  }
}

// ---------------------------------------------------------------- K7: GEMM2 [32768x256]@[256x128] + b2 -> raw y2 transposed into d_out, fused BN stats
__global__ __launch_bounds__(256) void gemm2_k(const bf16_t* __restrict__ A,
                                               const bf16_t* __restrict__ Bt,
                                               const float* __restrict__ bias,
                                               float* __restrict__ OUT,
                                               float* __restrict__ st) {
  const int K = 256;
  __shared__ bf16_t As[128 * 32];
  __shared__ bf16_t Bs[128 * 32];
  int tid = threadIdx.x, lane = tid & 63, w = tid >> 6;
  int wr = w >> 1, wc = w & 1;
  int m0 = blockIdx.x * 128;
  int e0 = (w * 2 + 0) * 512 + lane * 8;
  int e1 = (w * 2 + 1) * 512 + lane * 8;
  int ra0 = e0 >> 5, ca0 = e0 & 31;
  int ra1 = e1 >> 5, ca1 = e1 & 31;
  f32x4 acc[4][4];
  f32x4 z = {0.f, 0.f, 0.f, 0.f};
#pragma unroll
  for (int i = 0; i < 4; ++i)
#pragma unroll
    for (int j = 0; j < 4; ++j) acc[i][j] = z;
  for (int k0 = 0; k0 < K; k0 += 32) {
    __syncthreads();
    gload16(A + (size_t)(m0 + ra0) * K + k0 + ca0, &As[e0]);
    gload16(A + (size_t)(m0 + ra1) * K + k0 + ca1, &As[e1]);
    gload16(Bt + (size_t)ra0 * K + k0 + ca0, &Bs[e0]);
    gload16(Bt + (size_t)ra1 * K + k0 + ca1, &Bs[e1]);
    __syncthreads();
    bf16x8 af[4], bfr[4];
    int arow = wr * 64 + (lane & 15);
    int brow = wc * 64 + (lane & 15);
    int kc = 8 * (lane >> 4);
#pragma unroll
    for (int i = 0; i < 4; ++i) af[i]  = *(const bf16x8*)&As[(arow + i * 16) * 32 + kc];
#pragma unroll
    for (int j = 0; j < 4; ++j) bfr[j] = *(const bf16x8*)&Bs[(brow + j * 16) * 32 + kc];
#pragma unroll
    for (int i = 0; i < 4; ++i)
#pragma unroll
      for (int j = 0; j < 4; ++j)
        acc[i][j] = __builtin_amdgcn_mfma_f32_16x16x32_bf16(af[i], bfr[j], acc[i][j], 0, 0, 0);
  }
#pragma unroll
  for (int j = 0; j < 4; ++j) {
    int col = wc * 64 + j * 16 + (lane & 15);
    float bv = bias[col];
    float sj = 0.f, ssj = 0.f;
#pragma unroll
    for (int i = 0; i < 4; ++i) {
      int r  = m0 + wr * 64 + i * 16 + ((lane >> 4) << 2);
      int bb = r >> 14, n = r & (N_ - 1);
      f32x4 v = acc[i][j];
#pragma unroll
      for (int q = 0; q < 4; ++q) {
        v[q] += bv;
        sj += v[q]; ssj += v[q] * v[q];
      }
      *(f32x4*)&OUT[((size_t)(bb * C2_ + col)) * N_ + n] = v;
    }
    sj  += __shfl_xor(sj, 16);  sj  += __shfl_xor(sj, 32);
    ssj += __shfl_xor(ssj, 16); ssj += __shfl_xor(ssj, 32);
    if ((lane >> 4) == 0) {
      atomicAdd(&st[col], sj);
      atomicAdd(&st[C2_ + col], ssj);
    }
  }
}

// ---------------------------------------------------------------- K8: in-place BN2+ReLU on d_out (BN finalize folded in)
__global__ __launch_bounds__(256) void bn2apply_k(float* __restrict__ OUT,
                                                  const float* __restrict__ st,
                                                  const float* __restrict__ g,
                                                  const float* __restrict__ be) {
  __shared__ float ab[2];
  int t = threadIdx.x;
  int c = (blockIdx.x >> 4) & 127;             // 16 blocks per (b,c) row
  if (t == 0) {
    const float invM = 1.f / (float)M_;
    float mu  = st[c] * invM;
    float var = fmaxf(st[C2_ + c] * invM - mu * mu, 0.f);
    float a = g[c] * rsqrtf(var + 1e-5f);
    ab[0] = a;
    ab[1] = be[c] - mu * a;
  }
  __syncthreads();
  float a = ab[0], s = ab[1];
  size_t i4 = (size_t)blockIdx.x * 256 + t;    // float4 index
  f32x4 v = *(f32x4*)&OUT[i4 * 4];
#pragma unroll
  for (int u = 0; u < 4; ++u) v[u] = fmaxf(a * v[u] + s, 0.f);
  *(f32x4*)&OUT[i4 * 4] = v;
}

// ---------------------------------------------------------------- launch
extern "C" void kernel_launch(void* const* d_in, const int* in_sizes, int n_in,
                              void* d_out, int out_size, void* d_ws, size_t ws_size,
                              hipStream_t stream) {
  const float* xyz1    = (const float*)d_in[0];
  const float* xyz2    = (const float*)d_in[1];
  const float* points1 = (const float*)d_in[2];
  const float* points2 = (const float*)d_in[3];
  const float* w1      = (const float*)d_in[4];
  const float* b1      = (const float*)d_in[5];
  const float* g1      = (const float*)d_in[6];
  const float* beta1   = (const float*)d_in[7];
  const float* w2      = (const float*)d_in[8];
  const float* b2      = (const float*)d_in[9];
  const float* g2      = (const float*)d_in[10];
  const float* beta2   = (const float*)d_in[11];
  float* out = (float*)d_out;

  char* p = (char*)d_ws;
  size_t off = 0;
  bf16_t* w1t = (bf16_t*)(p + off); off += (size_t)C1_ * 384 * 2;      // 196608
  bf16_t* w2t = (bf16_t*)(p + off); off += (size_t)C2_ * C1_ * 2;      // 65536
  float*  p2t = (float*)(p + off);  off += (size_t)B_ * S_ * D2_ * 4;  // 8388608
  bf16_t* X   = (bf16_t*)(p + off); off += (size_t)M_ * 384 * 2;       // 25165824
  bf16_t* Y1  = (bf16_t*)(p + off); off += (size_t)M_ * C1_ * 2;       // 16777216
  bf16_t* X2  = (bf16_t*)(p + off); off += (size_t)M_ * C1_ * 2;       // 16777216
  float4* C4  = (float4*)(p + off); off += (size_t)B_ * S_ * 16;       // 131072
  float4* C4S = (float4*)(p + off); off += (size_t)B_ * S_ * 16;       // 131072
  int*    SIDX = (int*)(p + off);   off += (size_t)B_ * S_ * 4;        // 32768
  float4* Q4S = (float4*)(p + off); off += (size_t)B_ * N_ * 16;       // 524288
  int*    QID = (int*)(p + off);    off += (size_t)B_ * N_ * 4;        // 131072
  int*    CCNT = (int*)(p + off);   off += B_ * BINS_ * 4;             // 1024
  int*    QCNT = (int*)(p + off);   off += B_ * BINS_ * 4;             // 1024 (contig w/ CCNT)
  int*    CSTART = (int*)(p + off); off += (B_ * (BINS_ + 1) * 4 + 15) & ~15;
  int*    QSTART = (int*)(p + off); off += (B_ * (BINS_ + 1) * 4 + 15) & ~15;
  int*    CCUR = (int*)(p + off);   off += B_ * BINS_ * 4;
  int*    QCUR = (int*)(p + off);   off += B_ * BINS_ * 4;
  float*  ST1 = (float*)(p + off);  off += 2048;                       // 256 sum + 256 ss
  float*  ST2 = (float*)(p + off);  off += 1024;                       // 128 sum + 128 ss

  hipMemsetAsync(ST1, 0, 3072, stream);    // ST1 + ST2 contiguous
  hipMemsetAsync(CCNT, 0, 2048, stream);   // CCNT + QCNT contiguous

  setup_k<<<6720, 256, 0, stream>>>(points2, points1, w1, w2, xyz2, xyz1,
                                    p2t, X, w1t, w2t, C4, CCNT, QCNT);
  scan2_k<<<1, 256, 0, stream>>>(CCNT, QCNT, CSTART, QSTART, CCUR, QCUR);
  scatterc_k<<<16, 512, 0, stream>>>(C4, CCUR, C4S, SIDX);
  scatterq_k<<<64, 512, 0, stream>>>(xyz1, QCUR, Q4S, QID);
  knn3_k<<<1024, 512, 0, stream>>>(Q4S, QID, C4S, SIDX, CSTART, p2t, X);
  gemm1_k<<<dim3(M_ / 128, 2), 256, 0, stream>>>(X, w1t, b1, Y1, ST1);
  bn1apply_k<<<512, 256, 0, stream>>>(Y1, ST1, g1, beta1, X2);
  gemm2_k<<<M_ / 128, 256, 0, stream>>>(X2, w2t, b2, out, ST2);
  bn2apply_k<<<4096, 256, 0, stream>>>(out, ST2, g2, beta2);
}

// Round 7
// 221.478 us; speedup vs baseline: 6.5130x; 1.0222x over previous
//
#include <hip/hip_runtime.h>

#define B_   2
#define N_   16384
#define S_   4096
#define D1_  128
#define D2_  256
#define C1_  256
#define C2_  128
#define M_   (B_ * N_)   // 32768 rows

#define GMIN  (-4.0f)
#define BINS_ 128
#define BH_   (0.0625f)
#define BINV_ (16.0f)

typedef __bf16 bf16_t;
typedef bf16_t bf16x8 __attribute__((ext_vector_type(8)));
typedef bf16_t bf16x4 __attribute__((ext_vector_type(4)));
typedef float  f32x4  __attribute__((ext_vector_type(4)));

// ---------------------------------------------------------------- helpers
__device__ __forceinline__ void gload16(const void* g, void* l) {
  __builtin_amdgcn_global_load_lds(
      (const __attribute__((address_space(1))) void*)g,
      (__attribute__((address_space(3))) void*)l, 16, 0, 0);
}

__device__ __forceinline__ float med3f(float a, float b, float c) {
  float d;
  asm("v_med3_f32 %0, %1, %2, %3" : "=v"(d) : "v"(a), "v"(b), "v"(c));
  return d;
}

__device__ __forceinline__ int binof(float x) {
  int c = (int)floorf((x - GMIN) * BINV_);
  return min(BINS_ - 1, max(0, c));
}

// ---------------------------------------------------------------- K0: setup
// blocks [0,2048): points2 transpose -> p2t [B][4096][256]
// blocks [2048,6144): points1 transpose -> X[r][0:128) bf16 (row stride 384)
// blocks [6144,6688): w1t/w2t bf16 + c4 (-2x,-2y,-2z,|c|^2) + candidate x-bin counts
// blocks [6688,6720): query x-bin counts (LDS hist)
__global__ __launch_bounds__(256) void setup_k(const float* __restrict__ points2,
                                               const float* __restrict__ points1,
                                               const float* __restrict__ w1,
                                               const float* __restrict__ w2,
                                               const float* __restrict__ xyz2,
                                               const float* __restrict__ xyz1,
                                               float* __restrict__ p2t,
                                               bf16_t* __restrict__ X,
                                               bf16_t* __restrict__ w1t,
                                               bf16_t* __restrict__ w2t,
                                               float4* __restrict__ c4,
                                               int* __restrict__ ccnt,
                                               int* __restrict__ qcnt) {
  __shared__ float tile[32][33];
  __shared__ int hist[BINS_];
  int bi = blockIdx.x, t = threadIdx.x;
  int tx = t & 31, ty = t >> 5;
  if (bi < 2048) {
    int b = bi >> 10, rest = bi & 1023;
    int s0 = (rest & 127) * 32, c0 = (rest >> 7) * 32;
    const float* src = points2 + (size_t)b * D2_ * S_;
#pragma unroll
    for (int k = 0; k < 4; ++k)
      tile[ty + k * 8][tx] = src[(size_t)(c0 + ty + k * 8) * S_ + s0 + tx];
    __syncthreads();
    float* dst = p2t + (size_t)b * S_ * D2_;
#pragma unroll
    for (int k = 0; k < 4; ++k)
      dst[(size_t)(s0 + ty + k * 8) * D2_ + c0 + tx] = tile[tx][ty + k * 8];
  } else if (bi < 6144) {
    int bj = bi - 2048;
    int b = bj >> 11, rest = bj & 2047;
    int n0 = (rest & 511) * 32, c0 = (rest >> 9) * 32;
    const float* src = points1 + (size_t)b * D1_ * N_;
#pragma unroll
    for (int k = 0; k < 4; ++k)
      tile[ty + k * 8][tx] = src[(size_t)(c0 + ty + k * 8) * N_ + n0 + tx];
    __syncthreads();
#pragma unroll
    for (int k = 0; k < 4; ++k)
      X[(size_t)(b * N_ + n0 + ty + k * 8) * 384 + c0 + tx] = (bf16_t)tile[tx][ty + k * 8];
  } else if (bi < 6688) {
    int i = (bi - 6144) * 256 + t;
    if (i < C1_ * 384) {                       // w1t[n][k] = w1[k][n]
      int n = i / 384, k = i % 384;
      w1t[i] = (bf16_t)w1[(size_t)k * C1_ + n];
    } else if (i < C1_ * 384 + C2_ * C1_) {
      int j = i - C1_ * 384;                   // w2t[n][k] = w2[k][n]
      int n = j / C1_, k = j % C1_;
      w2t[j] = (bf16_t)w2[(size_t)k * C2_ + n];
    } else {
      int j = i - (C1_ * 384 + C2_ * C1_);     // 0 .. B*S-1
      int b = j >> 12, s = j & (S_ - 1);
      const float* X2p = xyz2 + (size_t)b * 3 * S_;
      float x = X2p[s], y = X2p[S_ + s], z = X2p[2 * S_ + s];
      c4[j] = make_float4(-2.f * x, -2.f * y, -2.f * z, x * x + y * y + z * z);
      atomicAdd(&ccnt[b * BINS_ + binof(x)], 1);
    }
  } else {
    int gq0 = (bi - 6688) * 1024;              // 1024 queries per block
    int b = gq0 >> 14;
    if (t < BINS_) hist[t] = 0;
    __syncthreads();
    const float* X1 = xyz1 + (size_t)b * 3 * N_;
#pragma unroll
    for (int u = 0; u < 4; ++u) {
      int n = (gq0 & (N_ - 1)) + t + u * 256;
      atomicAdd(&hist[binof(X1[n])], 1);
    }
    __syncthreads();
    if (t < BINS_) atomicAdd(&qcnt[b * BINS_ + t], hist[t]);
  }
}

// ---------------------------------------------------------------- K1: exclusive scans (4 arrays of 128)
__global__ __launch_bounds__(256) void scan2_k(const int* __restrict__ ccnt,
                                               const int* __restrict__ qcnt,
                                               int* __restrict__ cstart,
                                               int* __restrict__ qstart,
                                               int* __restrict__ ccur,
                                               int* __restrict__ qcur) {
  __shared__ int ss[4][64];
  int t = threadIdx.x, wv = t >> 6, l = t & 63;
  const int* cnt = (wv < 2) ? (ccnt + wv * BINS_) : (qcnt + (wv - 2) * BINS_);
  int* st = (wv < 2) ? (cstart + wv * (BINS_ + 1)) : (qstart + (wv - 2) * (BINS_ + 1));
  int* cu = (wv < 2) ? (ccur + wv * BINS_) : (qcur + (wv - 2) * BINS_);
  int c0 = cnt[l * 2], c1 = cnt[l * 2 + 1];
  int sum = c0 + c1;
  ss[wv][l] = sum;
  __syncthreads();
  int acc = 0;
  for (int i = 0; i < l; ++i) acc += ss[wv][i];
  st[l * 2] = acc;         cu[l * 2] = acc;
  st[l * 2 + 1] = acc + c0; cu[l * 2 + 1] = acc + c0;
  if (l == 63) st[BINS_] = acc + sum;
}

// ---------------------------------------------------------------- K2: scatter candidates + queries by x-bin (merged)
__global__ __launch_bounds__(512) void scatter_k(const float4* __restrict__ c4,
                                                 const float* __restrict__ xyz1,
                                                 int* __restrict__ ccur,
                                                 int* __restrict__ qcur,
                                                 float4* __restrict__ c4s,
                                                 int* __restrict__ sidx,
                                                 float4* __restrict__ q4s,
                                                 int* __restrict__ qid) {
  int bi = blockIdx.x;
  if (bi < 16) {
    int j = bi * 512 + threadIdx.x;            // candidate 0 .. 8191
    int b = j >> 12, s = j & (S_ - 1);
    float4 c = c4[j];
    int bin = binof(c.x * -0.5f);
    int pos = atomicAdd(&ccur[b * BINS_ + bin], 1);
    c4s[b * S_ + pos] = c;
    sidx[b * S_ + pos] = s;
  } else {
    int gq = (bi - 16) * 512 + threadIdx.x;    // query 0 .. 32767
    int b = gq >> 14, n = gq & (N_ - 1);
    const float* X1 = xyz1 + (size_t)b * 3 * N_;
    float ax = X1[n], ay = X1[N_ + n], az = X1[2 * N_ + n];
    float p = ax * ax + ay * ay + az * az;
    int bin = binof(ax);
    int pos = atomicAdd(&qcur[b * BINS_ + bin], 1);
    q4s[b * N_ + pos] = make_float4(ax, ay, az, p);
    qid[b * N_ + pos] = n;
  }
}

// ---------------------------------------------------------------- K3: windowed exact 3-NN + fused weighted gather
#define INSERT3(v, ix)                                                   \
  {                                                                      \
    bool b0_ = (v) < m0, b1_ = (v) < m1, b2_ = (v) < m2;                 \
    float nm0 = fminf((v), m0);                                          \
    float nm1 = med3f(m0, (v), m1);                                      \
    float nm2 = med3f(m1, (v), m2);                                      \
    j2 = b1_ ? j1 : (b2_ ? (ix) : j2);                                   \
    j1 = b0_ ? j0 : (b1_ ? (ix) : j1);                                   \
    j0 = b0_ ? (ix) : j0;                                                \
    m0 = nm0; m1 = nm1; m2 = nm2;                                        \
  }

// 1024 blocks x 512 threads (8 waves, no LDS). Wave: 4 sorted queries x 16 lanes.
// Window = union over wave of per-query adaptive slabs; flat uniform inner loop.
__global__ __launch_bounds__(512, 8) void knn4_k(const float4* __restrict__ q4s,
                                                 const int* __restrict__ qid,
                                                 const float4* __restrict__ c4s,
                                                 const int* __restrict__ sidx,
                                                 const int* __restrict__ cstart,
                                                 const float* __restrict__ p2t,
                                                 bf16_t* __restrict__ X) {
  int t = threadIdx.x, wv = t >> 6, l = t & 63;
  int grp = l >> 4, cslot = l & 15;
  int b = blockIdx.x >> 9;                      // 512 blocks per batch
  int spos = (blockIdx.x & 511) * 32 + wv * 4 + grp;
  float4 q = q4s[(size_t)b * N_ + spos];
  int qidx = qid[(size_t)b * N_ + spos];
  float ax = q.x, ay = q.y, az = q.z, p = q.w;
  float negp = -p;
  const float4* cb = c4s + (size_t)b * S_;
  const int*    ib = sidx + b * S_;
  const int*    sb = cstart + b * (BINS_ + 1);
  // adaptive window: ball of radius W holds ~12 expected candidates
  float W = fminf(0.223f * __expf(p * 0.1666667f), 4.0f);
  int b0 = binof(ax - W), b1 = binof(ax + W);
  // wave-union window -> uniform loop bounds
  int b0w = b0, b1w = b1;
  b0w = min(b0w, __shfl_xor(b0w, 16)); b0w = min(b0w, __shfl_xor(b0w, 32));
  b1w = max(b1w, __shfl_xor(b1w, 16)); b1w = max(b1w, __shfl_xor(b1w, 32));
  b0w = __builtin_amdgcn_readfirstlane(b0w);
  b1w = __builtin_amdgcn_readfirstlane(b1w);
  int s0 = __builtin_amdgcn_readfirstlane(sb[b0w]);
  int s1 = __builtin_amdgcn_readfirstlane(sb[b1w + 1]);
  float m0 = 3e38f, m1 = 3e38f, m2 = 3e38f;
  int   j0 = 0, j1 = 0, j2 = 0;
  for (int k = s0 + cslot; k < s1; k += 16) {
    float4 c = cb[k];
    float v = c.w;
    v = fmaf(az, c.z, v);
    v = fmaf(ay, c.y, v);
    v = fmaf(ax, c.x, v);
    v = fmaxf(v, negp);
    INSERT3(v, k);                              // track sorted position
  }
  // butterfly merge of the 16 lanes' top-3 lists
#pragma unroll
  for (int st = 1; st <= 8; st <<= 1) {
    float om0 = __shfl_xor(m0, st), om1 = __shfl_xor(m1, st), om2 = __shfl_xor(m2, st);
    int   oj0 = __shfl_xor(j0, st), oj1 = __shfl_xor(j1, st), oj2 = __shfl_xor(j2, st);
    INSERT3(om0, oj0);
    INSERT3(om1, oj1);
    INSERT3(om2, oj2);
  }
  // exact validation: any unscanned point has |dx| > W  =>  d > W^2
  bool allcov = (b0w == 0) && (b1w == BINS_ - 1);
  bool failed = (!allcov) && (p + m2 > W * W);
  if (__any(failed)) {
    if (failed) { m0 = m1 = m2 = 3e38f; j0 = j1 = j2 = 0; }
    for (int k = cslot; k < S_; k += 16) {
      float4 c = cb[k];
      float v = c.w;
      v = fmaf(az, c.z, v);
      v = fmaf(ay, c.y, v);
      v = fmaf(ax, c.x, v);
      v = fmaxf(v, negp);
      v = failed ? v : 3e38f;                   // inert for non-failed groups
      INSERT3(v, k);
    }
#pragma unroll
    for (int st = 1; st <= 8; st <<= 1) {
      float om0 = __shfl_xor(m0, st), om1 = __shfl_xor(m1, st), om2 = __shfl_xor(m2, st);
      int   oj0 = __shfl_xor(j0, st), oj1 = __shfl_xor(j1, st), oj2 = __shfl_xor(j2, st);
      om0 = failed ? om0 : 3e38f;
      om1 = failed ? om1 : 3e38f;
      om2 = failed ? om2 : 3e38f;
      INSERT3(om0, oj0);
      INSERT3(om1, oj1);
      INSERT3(om2, oj2);
    }
  }
  // weights
  float d0 = fmaxf(p + m0, 1e-6f);
  float d1 = fmaxf(p + m1, 1e-6f);
  float d2 = fmaxf(p + m2, 1e-6f);
  float r0 = 1.f / d0, r1 = 1.f / d1, r2 = 1.f / d2;
  float dn = fmaxf(r0 + r1 + r2, 1e-6f);
  float w0 = r0 / dn, w1 = r1 / dn, w2 = r2 / dn;
  // sorted position -> original candidate row
  int i0 = ib[j0], i1 = ib[j1], i2 = ib[j2];
  // fused gather: 16 channels per lane
  int c0ch = cslot * 16;
  const float* pb = p2t + (size_t)b * S_ * D2_;
  const float4* A4 = (const float4*)(pb + (size_t)i0 * D2_ + c0ch);
  const float4* B4 = (const float4*)(pb + (size_t)i1 * D2_ + c0ch);
  const float4* C4p = (const float4*)(pb + (size_t)i2 * D2_ + c0ch);
  bf16_t* xo = X + ((size_t)(b * N_ + qidx)) * 384 + 128 + c0ch;
#pragma unroll
  for (int u = 0; u < 4; ++u) {
    float4 A = A4[u], Bv = B4[u], Cv = C4p[u];
    bf16x4 o;
    o[0] = (bf16_t)(w0 * A.x + w1 * Bv.x + w2 * Cv.x);
    o[1] = (bf16_t)(w0 * A.y + w1 * Bv.y + w2 * Cv.y);
    o[2] = (bf16_t)(w0 * A.z + w1 * Bv.z + w2 * Cv.z);
    o[3] = (bf16_t)(w0 * A.w + w1 * Bv.w + w2 * Cv.w);
    *(bf16x4*)&xo[u * 4] = o;
  }
}

// ---------------------------------------------------------------- K4: GEMM1 [32768x384]@[384x256] + b1 -> y1 bf16, fused BN stats
__global__ __launch_bounds__(256) void gemm1_k(const bf16_t* __restrict__ A,
                                               const bf16_t* __restrict__ Bt,
                                               const float* __restrict__ bias,
                                               bf16_t* __restrict__ Y,
                                               float* __restrict__ st) {
  const int K = 384;
  __shared__ bf16_t As[128 * 32];
  __shared__ bf16_t Bs[128 * 32];
  int tid = threadIdx.x, lane = tid & 63, w = tid >> 6;
  int wr = w >> 1, wc = w & 1;
  int m0 = blockIdx.x * 128, n0 = blockIdx.y * 128;
  int e0 = (w * 2 + 0) * 512 + lane * 8;
  int e1 = (w * 2 + 1) * 512 + lane * 8;
  int ra0 = e0 >> 5, ca0 = e0 & 31;
  int ra1 = e1 >> 5, ca1 = e1 & 31;
  f32x4 acc[4][4];
  f32x4 z = {0.f, 0.f, 0.f, 0.f};
#pragma unroll
  for (int i = 0; i < 4; ++i)
#pragma unroll
    for (int j = 0; j < 4; ++j) acc[i][j] = z;
  for (int k0 = 0; k0 < K; k0 += 32) {
    __syncthreads();
    gload16(A + (size_t)(m0 + ra0) * K + k0 + ca0, &As[e0]);
    gload16(A + (size_t)(m0 + ra1) * K + k0 + ca1, &As[e1]);
    gload16(Bt + (size_t)(n0 + ra0) * K + k0 + ca0, &Bs[e0]);
    gload16(Bt + (size_t)(n0 + ra1) * K + k0 + ca1, &Bs[e1]);
    __syncthreads();
    bf16x8 af[4], bfr[4];
    int arow = wr * 64 + (lane & 15);
    int brow = wc * 64 + (lane & 15);
    int kc = 8 * (lane >> 4);
#pragma unroll
    for (int i = 0; i < 4; ++i) af[i]  = *(const bf16x8*)&As[(arow + i * 16) * 32 + kc];
#pragma unroll
    for (int j = 0; j < 4; ++j) bfr[j] = *(const bf16x8*)&Bs[(brow + j * 16) * 32 + kc];
#pragma unroll
    for (int i = 0; i < 4; ++i)
#pragma unroll
      for (int j = 0; j < 4; ++j)
        acc[i][j] = __builtin_amdgcn_mfma_f32_16x16x32_bf16(af[i], bfr[j], acc[i][j], 0, 0, 0);
  }
#pragma unroll
  for (int j = 0; j < 4; ++j) {
    int col = n0 + wc * 64 + j * 16 + (lane & 15);
    float bv = bias[col];
    float sj = 0.f, ssj = 0.f;
#pragma unroll
    for (int i = 0; i < 4; ++i) {
      int r = m0 + wr * 64 + i * 16 + ((lane >> 4) << 2);
#pragma unroll
      for (int q = 0; q < 4; ++q) {
        float y = acc[i][j][q] + bv;
        Y[(size_t)(r + q) * C1_ + col] = (bf16_t)y;
        sj += y; ssj += y * y;
      }
    }
    sj  += __shfl_xor(sj, 16);  sj  += __shfl_xor(sj, 32);
    ssj += __shfl_xor(ssj, 16); ssj += __shfl_xor(ssj, 32);
    if ((lane >> 4) == 0) {
      atomicAdd(&st[col], sj);
      atomicAdd(&st[C1_ + col], ssj);
    }
  }
}

// ---------------------------------------------------------------- K5: x2 = relu(a*y1+s) bf16 (BN finalize folded in)
__global__ __launch_bounds__(256) void bn1apply_k(const bf16_t* __restrict__ Y,
                                                  const float* __restrict__ st,
                                                  const float* __restrict__ g,
                                                  const float* __restrict__ be,
                                                  bf16_t* __restrict__ X2) {
  __shared__ float sa[256], sb[256];
  int t = threadIdx.x;
  {
    const float invM = 1.f / (float)M_;
    float mu  = st[t] * invM;
    float var = fmaxf(st[C1_ + t] * invM - mu * mu, 0.f);
    float a = g[t] * rsqrtf(var + 1e-5f);
    sa[t] = a;
    sb[t] = be[t] - mu * a;
  }
  __syncthreads();
  int cc = (t & 31) * 8;
  float a[8], s[8];
#pragma unroll
  for (int u = 0; u < 8; ++u) { a[u] = sa[cc + u]; s[u] = sb[cc + u]; }
  int r0 = blockIdx.x * 64 + (t >> 5);
  for (int it = 0; it < 8; ++it) {
    int r = r0 + it * 8;
    bf16x8 v = *(const bf16x8*)&Y[(size_t)r * C1_ + cc];
    bf16x8 o;
#pragma unroll
    for (int u = 0; u < 8; ++u) {
      float f = (float)v[u];
      f = fmaxf(a[u] * f + s[u], 0.f);
      o[u] = (bf16_t)f;
    }
    *(bf16x8*)&X2[(size_t)r * C1_ + cc] = o;
  }
}

// ---------------------------------------------------------------- K6: GEMM2 [32768x256]@[256x128] + b2 -> raw y2 transposed into d_out, fused BN stats
__global__ __launch_bounds__(256) void gemm2_k(const bf16_t* __restrict__ A,
                                               const bf16_t* __restrict__ Bt,
                                               const float* __restrict__ bias,
                                               float* __restrict__ OUT,
                                               float* __restrict__ st) {
  const int K = 256;
  __shared__ bf16_t As[128 * 32];
  __shared__ bf16_t Bs[128 * 32];
  int tid = threadIdx.x, lane = tid & 63, w = tid >> 6;
  int wr = w >> 1, wc = w & 1;
  int m0 = blockIdx.x * 128;
  int e0 = (w * 2 + 0) * 512 + lane * 8;
  int e1 = (w * 2 + 1) * 512 + lane * 8;
  int ra0 = e0 >> 5, ca0 = e0 & 31;
  int ra1 = e1 >> 5, ca1 = e1 & 31;
  f32x4 acc[4][4];
  f32x4 z = {0.f, 0.f, 0.f, 0.f};
#pragma unroll
  for (int i = 0; i < 4; ++i)
#pragma unroll
    for (int j = 0; j < 4; ++j) acc[i][j] = z;
  for (int k0 = 0; k0 < K; k0 += 32) {
    __syncthreads();
    gload16(A + (size_t)(m0 + ra0) * K + k0 + ca0, &As[e0]);
    gload16(A + (size_t)(m0 + ra1) * K + k0 + ca1, &As[e1]);
    gload16(Bt + (size_t)ra0 * K + k0 + ca0, &Bs[e0]);
    gload16(Bt + (size_t)ra1 * K + k0 + ca1, &Bs[e1]);
    __syncthreads();
    bf16x8 af[4], bfr[4];
    int arow = wr * 64 + (lane & 15);
    int brow = wc * 64 + (lane & 15);
    int kc = 8 * (lane >> 4);
#pragma unroll
    for (int i = 0; i < 4; ++i) af[i]  = *(const bf16x8*)&As[(arow + i * 16) * 32 + kc];
#pragma unroll
    for (int j = 0; j < 4; ++j) bfr[j] = *(const bf16x8*)&Bs[(brow + j * 16) * 32 + kc];
#pragma unroll
    for (int i = 0; i < 4; ++i)
#pragma unroll
      for (int j = 0; j < 4; ++j)
        acc[i][j] = __builtin_amdgcn_mfma_f32_16x16x32_bf16(af[i], bfr[j], acc[i][j], 0, 0, 0);
  }
#pragma unroll
  for (int j = 0; j < 4; ++j) {
    int col = wc * 64 + j * 16 + (lane & 15);
    float bv = bias[col];
    float sj = 0.f, ssj = 0.f;
#pragma unroll
    for (int i = 0; i < 4; ++i) {
      int r  = m0 + wr * 64 + i * 16 + ((lane >> 4) << 2);
      int bb = r >> 14, n = r & (N_ - 1);
      f32x4 v = acc[i][j];
#pragma unroll
      for (int q = 0; q < 4; ++q) {
        v[q] += bv;
        sj += v[q]; ssj += v[q] * v[q];
      }
      *(f32x4*)&OUT[((size_t)(bb * C2_ + col)) * N_ + n] = v;
    }
    sj  += __shfl_xor(sj, 16);  sj  += __shfl_xor(sj, 32);
    ssj += __shfl_xor(ssj, 16); ssj += __shfl_xor(ssj, 32);
    if ((lane >> 4) == 0) {
      atomicAdd(&st[col], sj);
      atomicAdd(&st[C2_ + col], ssj);
    }
  }
}

// ---------------------------------------------------------------- K7: in-place BN2+ReLU on d_out (BN finalize folded in)
__global__ __launch_bounds__(256) void bn2apply_k(float* __restrict__ OUT,
                                                  const float* __restrict__ st,
                                                  const float* __restrict__ g,
                                                  const float* __restrict__ be) {
  __shared__ float ab[2];
  int t = threadIdx.x;
  int c = (blockIdx.x >> 4) & 127;             // 16 blocks per (b,c) row
  if (t == 0) {
    const float invM = 1.f / (float)M_;
    float mu  = st[c] * invM;
    float var = fmaxf(st[C2_ + c] * invM - mu * mu, 0.f);
    float a = g[c] * rsqrtf(var + 1e-5f);
    ab[0] = a;
    ab[1] = be[c] - mu * a;
  }
  __syncthreads();
  float a = ab[0], s = ab[1];
  size_t i4 = (size_t)blockIdx.x * 256 + t;    // float4 index
  f32x4 v = *(f32x4*)&OUT[i4 * 4];
#pragma unroll
  for (int u = 0; u < 4; ++u) v[u] = fmaxf(a * v[u] + s, 0.f);
  *(f32x4*)&OUT[i4 * 4] = v;
}

// ---------------------------------------------------------------- launch
extern "C" void kernel_launch(void* const* d_in, const int* in_sizes, int n_in,
                              void* d_out, int out_size, void* d_ws, size_t ws_size,
                              hipStream_t stream) {
  const float* xyz1    = (const float*)d_in[0];
  const float* xyz2    = (const float*)d_in[1];
  const float* points1 = (const float*)d_in[2];
  const float* points2 = (const float*)d_in[3];
  const float* w1      = (const float*)d_in[4];
  const float* b1      = (const float*)d_in[5];
  const float* g1      = (const float*)d_in[6];
  const float* beta1   = (const float*)d_in[7];
  const float* w2      = (const float*)d_in[8];
  const float* b2      = (const float*)d_in[9];
  const float* g2      = (const float*)d_in[10];
  const float* beta2   = (const float*)d_in[11];
  float* out = (float*)d_out;

  char* p = (char*)d_ws;
  size_t off = 0;
  bf16_t* w1t = (bf16_t*)(p + off); off += (size_t)C1_ * 384 * 2;      // 196608
  bf16_t* w2t = (bf16_t*)(p + off); off += (size_t)C2_ * C1_ * 2;      // 65536
  float*  p2t = (float*)(p + off);  off += (size_t)B_ * S_ * D2_ * 4;  // 8388608
  bf16_t* X   = (bf16_t*)(p + off); off += (size_t)M_ * 384 * 2;       // 25165824
  bf16_t* Y1  = (bf16_t*)(p + off); off += (size_t)M_ * C1_ * 2;       // 16777216
  bf16_t* X2  = (bf16_t*)(p + off); off += (size_t)M_ * C1_ * 2;       // 16777216
  float4* C4  = (float4*)(p + off); off += (size_t)B_ * S_ * 16;       // 131072
  float4* C4S = (float4*)(p + off); off += (size_t)B_ * S_ * 16;       // 131072
  int*    SIDX = (int*)(p + off);   off += (size_t)B_ * S_ * 4;        // 32768
  float4* Q4S = (float4*)(p + off); off += (size_t)B_ * N_ * 16;       // 524288
  int*    QID = (int*)(p + off);    off += (size_t)B_ * N_ * 4;        // 131072
  int*    CCNT = (int*)(p + off);   off += B_ * BINS_ * 4;             // 1024
  int*    QCNT = (int*)(p + off);   off += B_ * BINS_ * 4;             // 1024 (contig w/ CCNT)
  int*    CSTART = (int*)(p + off); off += (B_ * (BINS_ + 1) * 4 + 15) & ~15;
  int*    QSTART = (int*)(p + off); off += (B_ * (BINS_ + 1) * 4 + 15) & ~15;
  int*    CCUR = (int*)(p + off);   off += B_ * BINS_ * 4;
  int*    QCUR = (int*)(p + off);   off += B_ * BINS_ * 4;
  float*  ST1 = (float*)(p + off);  off += 2048;                       // 256 sum + 256 ss
  float*  ST2 = (float*)(p + off);  off += 1024;                       // 128 sum + 128 ss

  hipMemsetAsync(ST1, 0, 3072, stream);    // ST1 + ST2 contiguous
  hipMemsetAsync(CCNT, 0, 2048, stream);   // CCNT + QCNT contiguous

  setup_k<<<6720, 256, 0, stream>>>(points2, points1, w1, w2, xyz2, xyz1,
                                    p2t, X, w1t, w2t, C4, CCNT, QCNT);
  scan2_k<<<1, 256, 0, stream>>>(CCNT, QCNT, CSTART, QSTART, CCUR, QCUR);
  scatter_k<<<80, 512, 0, stream>>>(C4, xyz1, CCUR, QCUR, C4S, SIDX, Q4S, QID);
  knn4_k<<<1024, 512, 0, stream>>>(Q4S, QID, C4S, SIDX, CSTART, p2t, X);
  gemm1_k<<<dim3(M_ / 128, 2), 256, 0, stream>>>(X, w1t, b1, Y1, ST1);
  bn1apply_k<<<512, 256, 0, stream>>>(Y1, ST1, g1, beta1, X2);
  gemm2_k<<<M_ / 128, 256, 0, stream>>>(X2, w2t, b2, out, ST2);
  bn2apply_k<<<4096, 256, 0, stream>>>(out, ST2, g2, beta2);
}

// Round 8
// 172.910 us; speedup vs baseline: 8.3424x; 1.2809x over previous
//
#include <hip/hip_runtime.h>

#define B_   2
#define N_   16384
#define S_   4096
#define D1_  128
#define D2_  256
#define C1_  256
#define C2_  128
#define M_   (B_ * N_)   // 32768 rows

typedef __bf16 bf16_t;
typedef bf16_t bf16x8 __attribute__((ext_vector_type(8)));
typedef float  f32x4  __attribute__((ext_vector_type(4)));

// ---------------------------------------------------------------- helpers
__device__ __forceinline__ void gload16(const void* g, void* l) {
  __builtin_amdgcn_global_load_lds(
      (const __attribute__((address_space(1))) void*)g,
      (__attribute__((address_space(3))) void*)l, 16, 0, 0);
}

// top-3 insert; med3 via min/max so compiler emits v_med3_f32
#define INSERT3(v, ix)                                                   \
  {                                                                      \
    bool b0_ = (v) < m0, b1_ = (v) < m1, b2_ = (v) < m2;                 \
    float nm0 = fminf((v), m0);                                          \
    float nm1 = fminf(fmaxf((v), m0), m1);                               \
    float nm2 = fminf(fmaxf((v), m1), m2);                               \
    j2 = b1_ ? j1 : (b2_ ? (ix) : j2);                                   \
    j1 = b0_ ? j0 : (b1_ ? (ix) : j1);                                   \
    j0 = b0_ ? (ix) : j0;                                                \
    m0 = nm0; m1 = nm1; m2 = nm2;                                        \
  }

// ---------------------------------------------------------------- K0: setup
// blocks [0,2048): points2 transpose -> p2tb bf16 [B][4096][256]
// blocks [2048,6144): points1 transpose -> Xp1 bf16 [M][128]
// blocks [6144,6688): w1at/w1bt/w2t bf16 [N][K] + c4 = (-2x,-2y,-2z,|c|^2)
__global__ __launch_bounds__(256) void setup_k(const float* __restrict__ points2,
                                               const float* __restrict__ points1,
                                               const float* __restrict__ w1,
                                               const float* __restrict__ w2,
                                               const float* __restrict__ xyz2,
                                               bf16_t* __restrict__ p2tb,
                                               bf16_t* __restrict__ Xp1,
                                               bf16_t* __restrict__ w1at,
                                               bf16_t* __restrict__ w1bt,
                                               bf16_t* __restrict__ w2t,
                                               float4* __restrict__ c4) {
  __shared__ float tile[32][33];
  int bi = blockIdx.x, t = threadIdx.x;
  int tx = t & 31, ty = t >> 5;
  if (bi < 2048) {
    int b = bi >> 10, rest = bi & 1023;
    int s0 = (rest & 127) * 32, c0 = (rest >> 7) * 32;
    const float* src = points2 + (size_t)b * D2_ * S_;
#pragma unroll
    for (int k = 0; k < 4; ++k)
      tile[ty + k * 8][tx] = src[(size_t)(c0 + ty + k * 8) * S_ + s0 + tx];
    __syncthreads();
    bf16_t* dst = p2tb + (size_t)b * S_ * D2_;
#pragma unroll
    for (int k = 0; k < 4; ++k)
      dst[(size_t)(s0 + ty + k * 8) * D2_ + c0 + tx] = (bf16_t)tile[tx][ty + k * 8];
  } else if (bi < 6144) {
    int bj = bi - 2048;
    int b = bj >> 11, rest = bj & 2047;
    int n0 = (rest & 511) * 32, c0 = (rest >> 9) * 32;
    const float* src = points1 + (size_t)b * D1_ * N_;
#pragma unroll
    for (int k = 0; k < 4; ++k)
      tile[ty + k * 8][tx] = src[(size_t)(c0 + ty + k * 8) * N_ + n0 + tx];
    __syncthreads();
#pragma unroll
    for (int k = 0; k < 4; ++k)
      Xp1[(size_t)(b * N_ + n0 + ty + k * 8) * 128 + c0 + tx] = (bf16_t)tile[tx][ty + k * 8];
  } else {
    int i = (bi - 6144) * 256 + t;
    if (i < 32768) {                            // w1at[n][k] = w1[k][n], k<128
      int n = i >> 7, k = i & 127;
      w1at[i] = (bf16_t)w1[(size_t)k * C1_ + n];
    } else if (i < 98304) {                     // w1bt[n][k] = w1[128+k][n]
      int j = i - 32768;
      int n = j >> 8, k = j & 255;
      w1bt[j] = (bf16_t)w1[(size_t)(128 + k) * C1_ + n];
    } else if (i < 131072) {                    // w2t[n][k] = w2[k][n]
      int j = i - 98304;
      int n = j >> 8, k = j & 255;
      w2t[j] = (bf16_t)w2[(size_t)k * C2_ + n];
    } else {                                    // c4
      int j = i - 131072;
      if (j < B_ * S_) {
        int b = j >> 12, s = j & (S_ - 1);
        const float* X2p = xyz2 + (size_t)b * 3 * S_;
        float x = X2p[s], y = X2p[S_ + s], z = X2p[2 * S_ + s];
        c4[j] = make_float4(-2.f * x, -2.f * y, -2.f * z, x * x + y * y + z * z);
      }
    }
  }
}

// ---------------------------------------------------------------- K1: G = p2t @ W1b  -> fp32 [B][4096][256]
__global__ __launch_bounds__(256) void gemmG_k(const bf16_t* __restrict__ A,
                                               const bf16_t* __restrict__ Bt,
                                               float* __restrict__ G) {
  const int K = 256;
  __shared__ bf16_t As[128 * 32];
  __shared__ bf16_t Bs[128 * 32];
  int tid = threadIdx.x, lane = tid & 63, w = tid >> 6;
  int wr = w >> 1, wc = w & 1;
  int z  = blockIdx.z;
  int m0 = blockIdx.x * 128, n0 = blockIdx.y * 128;
  const bf16_t* Ab = A + (size_t)z * S_ * 256;
  float* Gb = G + (size_t)z * S_ * 256;
  int e0 = (w * 2 + 0) * 512 + lane * 8;
  int e1 = (w * 2 + 1) * 512 + lane * 8;
  int ra0 = e0 >> 5, ca0 = e0 & 31;
  int ra1 = e1 >> 5, ca1 = e1 & 31;
  f32x4 acc[4][4];
  f32x4 zv = {0.f, 0.f, 0.f, 0.f};
#pragma unroll
  for (int i = 0; i < 4; ++i)
#pragma unroll
    for (int j = 0; j < 4; ++j) acc[i][j] = zv;
  for (int k0 = 0; k0 < K; k0 += 32) {
    __syncthreads();
    gload16(Ab + (size_t)(m0 + ra0) * K + k0 + ca0, &As[e0]);
    gload16(Ab + (size_t)(m0 + ra1) * K + k0 + ca1, &As[e1]);
    gload16(Bt + (size_t)(n0 + ra0) * K + k0 + ca0, &Bs[e0]);
    gload16(Bt + (size_t)(n0 + ra1) * K + k0 + ca1, &Bs[e1]);
    __syncthreads();
    bf16x8 af[4], bfr[4];
    int arow = wr * 64 + (lane & 15);
    int brow = wc * 64 + (lane & 15);
    int kc = 8 * (lane >> 4);
#pragma unroll
    for (int i = 0; i < 4; ++i) af[i]  = *(const bf16x8*)&As[(arow + i * 16) * 32 + kc];
#pragma unroll
    for (int j = 0; j < 4; ++j) bfr[j] = *(const bf16x8*)&Bs[(brow + j * 16) * 32 + kc];
#pragma unroll
    for (int i = 0; i < 4; ++i)
#pragma unroll
      for (int j = 0; j < 4; ++j)
        acc[i][j] = __builtin_amdgcn_mfma_f32_16x16x32_bf16(af[i], bfr[j], acc[i][j], 0, 0, 0);
  }
#pragma unroll
  for (int j = 0; j < 4; ++j) {
    int col = n0 + wc * 64 + j * 16 + (lane & 15);
#pragma unroll
    for (int i = 0; i < 4; ++i) {
      int r = m0 + wr * 64 + i * 16 + ((lane >> 4) << 2);
#pragma unroll
      for (int q = 0; q < 4; ++q)
        Gb[(size_t)(r + q) * 256 + col] = acc[i][j][q];
    }
  }
}

// ---------------------------------------------------------------- K2: brute-force exact 3-NN (R4 structure, pure)
__global__ __launch_bounds__(512, 8) void knn_k(const float* __restrict__ xyz1,
                                                const float4* __restrict__ c4,
                                                float* __restrict__ kw,
                                                int* __restrict__ ki) {
  __shared__ float4 cbuf[1024];                 // 16KB staging; reused for partials
  __shared__ float  T3V[2][3][32];
  __shared__ int    T3I[2][3][32];
  int t = threadIdx.x, l = t & 63, w = t >> 6;
  int q = l & 31, h = l >> 5;
  int s = w * 2 + h;                            // slice 0..15
  int b  = blockIdx.x >> 9;                     // 512 blocks per batch
  int nb = (blockIdx.x & 511) * 32;
  int n  = nb + q;
  const float* X1 = xyz1 + (size_t)b * 3 * N_;
  float ax = X1[n], ay = X1[N_ + n], az = X1[2 * N_ + n];
  float p = ax * ax + ay * ay + az * az;
  const float4* cb = c4 + (size_t)b * S_;
  float m0 = 3e38f, m1 = 3e38f, m2 = 3e38f;
  int   j0 = 0, j1 = 0, j2 = 0;
  for (int r = 0; r < 4; ++r) {
    __syncthreads();                            // prev round's scan done
    gload16(cb + r * 1024 + t,       (char*)cbuf + (size_t)t * 16);
    gload16(cb + r * 1024 + t + 512, (char*)cbuf + (size_t)(t + 512) * 16);
    __syncthreads();                            // staged data visible
    const float4* cs = cbuf + s * 64;
    int base = r * 1024 + s * 64;
#pragma unroll 8
    for (int i = 0; i < 64; ++i) {
      float4 c = cs[i];
      float v = c.w;
      v = fmaf(az, c.z, v);
      v = fmaf(ay, c.y, v);
      v = fmaf(ax, c.x, v);
      int idx = base + i;
      INSERT3(v, idx);
    }
  }
  __syncthreads();                              // all scans done; reuse cbuf
  float* SV = (float*)cbuf;                     // [16][3][32]
  int*   SI = (int*)cbuf + 1536;                // [16][3][32]
  SV[(s * 3 + 0) * 32 + q] = m0;  SV[(s * 3 + 1) * 32 + q] = m1;  SV[(s * 3 + 2) * 32 + q] = m2;
  SI[(s * 3 + 0) * 32 + q] = j0;  SI[(s * 3 + 1) * 32 + q] = j1;  SI[(s * 3 + 2) * 32 + q] = j2;
  __syncthreads();
  if (t < 64) {                                 // stage A: merge 8 slices each
    int th = t >> 5, tq = t & 31;
    float M0 = 3e38f, M1 = 3e38f, M2 = 3e38f;
    int   a0 = 0, a1 = 0, a2 = 0;
    {
      float m0 = M0, m1 = M1, m2 = M2;
      int j0 = a0, j1 = a1, j2 = a2;
      for (int s2 = th * 8; s2 < th * 8 + 8; ++s2)
#pragma unroll
        for (int k = 0; k < 3; ++k) {
          float v = SV[(s2 * 3 + k) * 32 + tq];
          int  ix = SI[(s2 * 3 + k) * 32 + tq];
          INSERT3(v, ix);
        }
      M0 = m0; M1 = m1; M2 = m2; a0 = j0; a1 = j1; a2 = j2;
    }
    T3V[th][0][tq] = M0; T3V[th][1][tq] = M1; T3V[th][2][tq] = M2;
    T3I[th][0][tq] = a0; T3I[th][1][tq] = a1; T3I[th][2][tq] = a2;
  }
  __syncthreads();
  if (t < 32) {                                 // stage B: final merge; t == own query
    float m0 = T3V[0][0][t], m1 = T3V[0][1][t], m2 = T3V[0][2][t];
    int   j0 = T3I[0][0][t], j1 = T3I[0][1][t], j2 = T3I[0][2][t];
#pragma unroll
    for (int k = 0; k < 3; ++k) {
      float v = T3V[1][k][t];
      int  ix = T3I[1][k][t];
      INSERT3(v, ix);
    }
    float d0 = fmaxf(p + m0, 1e-6f);
    float d1 = fmaxf(p + m1, 1e-6f);
    float d2 = fmaxf(p + m2, 1e-6f);
    float r0 = 1.f / d0, r1 = 1.f / d1, r2 = 1.f / d2;
    float dn = fmaxf(r0 + r1 + r2, 1e-6f);
    size_t rr = (size_t)b * N_ + n;
    kw[rr * 3 + 0] = r0 / dn;  kw[rr * 3 + 1] = r1 / dn;  kw[rr * 3 + 2] = r2 / dn;
    ki[rr * 3 + 0] = j0;       ki[rr * 3 + 1] = j1;       ki[rr * 3 + 2] = j2;
  }
}

// ---------------------------------------------------------------- K3: GEMM1 [32768x128]@[128x256] + b1 + Sum w_j G[i_j] -> y1 bf16, BN stats
__global__ __launch_bounds__(256) void gemm1_k(const bf16_t* __restrict__ A,
                                               const bf16_t* __restrict__ Bt,
                                               const float* __restrict__ bias,
                                               const float* __restrict__ G,
                                               const float* __restrict__ KW,
                                               const int* __restrict__ KI,
                                               bf16_t* __restrict__ Y,
                                               float* __restrict__ st) {
  const int K = 128;
  __shared__ bf16_t As[128 * 32];
  __shared__ bf16_t Bs[128 * 32];
  int tid = threadIdx.x, lane = tid & 63, w = tid >> 6;
  int wr = w >> 1, wc = w & 1;
  int m0 = blockIdx.x * 128, n0 = blockIdx.y * 128;
  int e0 = (w * 2 + 0) * 512 + lane * 8;
  int e1 = (w * 2 + 1) * 512 + lane * 8;
  int ra0 = e0 >> 5, ca0 = e0 & 31;
  int ra1 = e1 >> 5, ca1 = e1 & 31;
  f32x4 acc[4][4];
  f32x4 z = {0.f, 0.f, 0.f, 0.f};
#pragma unroll
  for (int i = 0; i < 4; ++i)
#pragma unroll
    for (int j = 0; j < 4; ++j) acc[i][j] = z;
  for (int k0 = 0; k0 < K; k0 += 32) {
    __syncthreads();
    gload16(A + (size_t)(m0 + ra0) * K + k0 + ca0, &As[e0]);
    gload16(A + (size_t)(m0 + ra1) * K + k0 + ca1, &As[e1]);
    gload16(Bt + (size_t)(n0 + ra0) * K + k0 + ca0, &Bs[e0]);
    gload16(Bt + (size_t)(n0 + ra1) * K + k0 + ca1, &Bs[e1]);
    __syncthreads();
    bf16x8 af[4], bfr[4];
    int arow = wr * 64 + (lane & 15);
    int brow = wc * 64 + (lane & 15);
    int kc = 8 * (lane >> 4);
#pragma unroll
    for (int i = 0; i < 4; ++i) af[i]  = *(const bf16x8*)&As[(arow + i * 16) * 32 + kc];
#pragma unroll
    for (int j = 0; j < 4; ++j) bfr[j] = *(const bf16x8*)&Bs[(brow + j * 16) * 32 + kc];
#pragma unroll
    for (int i = 0; i < 4; ++i)
#pragma unroll
      for (int j = 0; j < 4; ++j)
        acc[i][j] = __builtin_amdgcn_mfma_f32_16x16x32_bf16(af[i], bfr[j], acc[i][j], 0, 0, 0);
  }
  // stage this block's KW/KI into LDS (reuse As)
  __syncthreads();
  float* kwls = (float*)As;                   // 128*3 floats
  int*   kils = ((int*)As) + 384;             // 128*3 ints
  if (tid < 128) {
    int r = m0 + tid;
    kwls[tid * 3 + 0] = KW[(size_t)r * 3 + 0];
    kwls[tid * 3 + 1] = KW[(size_t)r * 3 + 1];
    kwls[tid * 3 + 2] = KW[(size_t)r * 3 + 2];
    kils[tid * 3 + 0] = KI[(size_t)r * 3 + 0];
    kils[tid * 3 + 1] = KI[(size_t)r * 3 + 1];
    kils[tid * 3 + 2] = KI[(size_t)r * 3 + 2];
  }
  __syncthreads();
  int bb = m0 >> 14;
  const float* Gb = G + (size_t)bb * S_ * 256;
  float sjv[4]  = {0.f, 0.f, 0.f, 0.f};
  float ssjv[4] = {0.f, 0.f, 0.f, 0.f};
#pragma unroll
  for (int i = 0; i < 4; ++i) {
#pragma unroll
    for (int qq = 0; qq < 4; ++qq) {
      int rl = wr * 64 + i * 16 + ((lane >> 4) << 2) + qq;
      float w0 = kwls[rl * 3 + 0], w1v = kwls[rl * 3 + 1], w2v = kwls[rl * 3 + 2];
      const float* g0 = Gb + (size_t)kils[rl * 3 + 0] * 256;
      const float* g1 = Gb + (size_t)kils[rl * 3 + 1] * 256;
      const float* g2 = Gb + (size_t)kils[rl * 3 + 2] * 256;
      int r = m0 + rl;
#pragma unroll
      for (int j = 0; j < 4; ++j) {
        int col = n0 + wc * 64 + j * 16 + (lane & 15);
        float y = acc[i][j][qq] + bias[col]
                + w0 * g0[col] + w1v * g1[col] + w2v * g2[col];
        Y[(size_t)r * C1_ + col] = (bf16_t)y;
        sjv[j] += y;  ssjv[j] += y * y;
      }
    }
  }
#pragma unroll
  for (int j = 0; j < 4; ++j) {
    float sj = sjv[j], ssj = ssjv[j];
    sj  += __shfl_xor(sj, 16);  sj  += __shfl_xor(sj, 32);
    ssj += __shfl_xor(ssj, 16); ssj += __shfl_xor(ssj, 32);
    if ((lane >> 4) == 0) {
      int col = n0 + wc * 64 + j * 16 + (lane & 15);
      atomicAdd(&st[col], sj);
      atomicAdd(&st[C1_ + col], ssj);
    }
  }
}

// ---------------------------------------------------------------- K4: GEMM2 with fused BN1(A-load) + raw transposed out + BN2 via grid barrier
__global__ __launch_bounds__(256, 2) void gemm2_k(const bf16_t* __restrict__ Y1,
                                                  const bf16_t* __restrict__ Bt,
                                                  const float* __restrict__ bias,
                                                  const float* __restrict__ st1,
                                                  const float* __restrict__ g1v,
                                                  const float* __restrict__ be1,
                                                  float* __restrict__ OUT,
                                                  float* __restrict__ st2,
                                                  const float* __restrict__ g2v,
                                                  const float* __restrict__ be2,
                                                  int* __restrict__ cnt) {
  const int K = 256;
  __shared__ bf16_t As[128 * 32];
  __shared__ bf16_t Bs[128 * 32];
  __shared__ float sa1[C1_], sb1[C1_];
  __shared__ float a2s[C2_], b2s[C2_];
  int tid = threadIdx.x, lane = tid & 63, w = tid >> 6;
  int wr = w >> 1, wc = w & 1;
  int m0 = blockIdx.x * 128;
  {                                             // BN1 coefficients (ST1 complete: prior kernel)
    const float invM = 1.f / (float)M_;
    float mu  = st1[tid] * invM;
    float var = fmaxf(st1[C1_ + tid] * invM - mu * mu, 0.f);
    float a = g1v[tid] * rsqrtf(var + 1e-5f);
    sa1[tid] = a;
    sb1[tid] = be1[tid] - mu * a;
  }
  int e0 = (w * 2 + 0) * 512 + lane * 8;
  int e1 = (w * 2 + 1) * 512 + lane * 8;
  int ra0 = e0 >> 5, ca0 = e0 & 31;
  int ra1 = e1 >> 5, ca1 = e1 & 31;
  f32x4 acc[4][4];
  f32x4 z = {0.f, 0.f, 0.f, 0.f};
#pragma unroll
  for (int i = 0; i < 4; ++i)
#pragma unroll
    for (int j = 0; j < 4; ++j) acc[i][j] = z;
  __syncthreads();                              // sa1/sb1 ready
  for (int k0 = 0; k0 < K; k0 += 32) {
    if (k0) __syncthreads();
    // reg-stage A with BN1+ReLU transform
    bf16x8 va0 = *(const bf16x8*)&Y1[(size_t)(m0 + ra0) * C1_ + k0 + ca0];
    bf16x8 va1 = *(const bf16x8*)&Y1[(size_t)(m0 + ra1) * C1_ + k0 + ca1];
    bf16x8 oa0, oa1;
#pragma unroll
    for (int u = 0; u < 8; ++u) {
      float f0 = (float)va0[u];
      float f1 = (float)va1[u];
      f0 = fmaxf(f0 * sa1[k0 + ca0 + u] + sb1[k0 + ca0 + u], 0.f);
      f1 = fmaxf(f1 * sa1[k0 + ca1 + u] + sb1[k0 + ca1 + u], 0.f);
      oa0[u] = (bf16_t)f0;
      oa1[u] = (bf16_t)f1;
    }
    *(bf16x8*)&As[e0] = oa0;
    *(bf16x8*)&As[e1] = oa1;
    gload16(Bt + (size_t)ra0 * K + k0 + ca0, &Bs[e0]);
    gload16(Bt + (size_t)ra1 * K + k0 + ca1, &Bs[e1]);
    __syncthreads();
    bf16x8 af[4], bfr[4];
    int arow = wr * 64 + (lane & 15);
    int brow = wc * 64 + (lane & 15);
    int kc = 8 * (lane >> 4);
#pragma unroll
    for (int i = 0; i < 4; ++i) af[i]  = *(const bf16x8*)&As[(arow + i * 16) * 32 + kc];
#pragma unroll
    for (int j = 0; j < 4; ++j) bfr[j] = *(const bf16x8*)&Bs[(brow + j * 16) * 32 + kc];
#pragma unroll
    for (int i = 0; i < 4; ++i)
#pragma unroll
      for (int j = 0; j < 4; ++j)
        acc[i][j] = __builtin_amdgcn_mfma_f32_16x16x32_bf16(af[i], bfr[j], acc[i][j], 0, 0, 0);
  }
#pragma unroll
  for (int j = 0; j < 4; ++j) {
    int col = wc * 64 + j * 16 + (lane & 15);
    float bv = bias[col];
    float sj = 0.f, ssj = 0.f;
#pragma unroll
    for (int i = 0; i < 4; ++i) {
      int r  = m0 + wr * 64 + i * 16 + ((lane >> 4) << 2);
      int bb = r >> 14, n = r & (N_ - 1);
      f32x4 v = acc[i][j];
#pragma unroll
      for (int q = 0; q < 4; ++q) {
        v[q] += bv;
        sj += v[q]; ssj += v[q] * v[q];
      }
      *(f32x4*)&OUT[((size_t)(bb * C2_ + col)) * N_ + n] = v;
    }
    sj  += __shfl_xor(sj, 16);  sj  += __shfl_xor(sj, 32);
    ssj += __shfl_xor(ssj, 16); ssj += __shfl_xor(ssj, 32);
    if ((lane >> 4) == 0) {
      atomicAdd(&st2[col], sj);
      atomicAdd(&st2[C2_ + col], ssj);
    }
  }
  // ---- grid barrier (256 blocks, >=2 blocks/CU capacity => all co-resident)
  __syncthreads();                              // drains this block's stores+atomics
  if (tid == 0) {
    __threadfence();
    atomicAdd(cnt, 1);
    while (__hip_atomic_load(cnt, __ATOMIC_ACQUIRE, __HIP_MEMORY_SCOPE_AGENT) < (int)gridDim.x)
      __builtin_amdgcn_s_sleep(8);
  }
  __syncthreads();
  // ---- BN2 finalize + in-place apply on own tile
  if (tid < C2_) {
    float s  = __hip_atomic_load(&st2[tid],        __ATOMIC_RELAXED, __HIP_MEMORY_SCOPE_AGENT);
    float ss = __hip_atomic_load(&st2[C2_ + tid],  __ATOMIC_RELAXED, __HIP_MEMORY_SCOPE_AGENT);
    const float invM = 1.f / (float)M_;
    float mu  = s * invM;
    float var = fmaxf(ss * invM - mu * mu, 0.f);
    float a = g2v[tid] * rsqrtf(var + 1e-5f);
    a2s[tid] = a;
    b2s[tid] = be2[tid] - mu * a;
  }
  __syncthreads();
  int bb = m0 >> 14, ng = m0 & (N_ - 1);
  int c = tid >> 1, half = tid & 1;
  float a = a2s[c], sft = b2s[c];
  float* pr = OUT + ((size_t)(bb * C2_ + c)) * N_ + ng + half * 64;
#pragma unroll
  for (int u2 = 0; u2 < 16; ++u2) {
    f32x4 v = *(f32x4*)&pr[u2 * 4];
#pragma unroll
    for (int u = 0; u < 4; ++u) v[u] = fmaxf(a * v[u] + sft, 0.f);
    *(f32x4*)&pr[u2 * 4] = v;
  }
}

// ---------------------------------------------------------------- launch
extern "C" void kernel_launch(void* const* d_in, const int* in_sizes, int n_in,
                              void* d_out, int out_size, void* d_ws, size_t ws_size,
                              hipStream_t stream) {
  const float* xyz1    = (const float*)d_in[0];
  const float* xyz2    = (const float*)d_in[1];
  const float* points1 = (const float*)d_in[2];
  const float* points2 = (const float*)d_in[3];
  const float* w1      = (const float*)d_in[4];
  const float* b1      = (const float*)d_in[5];
  const float* g1      = (const float*)d_in[6];
  const float* beta1   = (const float*)d_in[7];
  const float* w2      = (const float*)d_in[8];
  const float* b2      = (const float*)d_in[9];
  const float* g2      = (const float*)d_in[10];
  const float* beta2   = (const float*)d_in[11];
  float* out = (float*)d_out;

  char* p = (char*)d_ws;
  size_t off = 0;
  bf16_t* Xp1  = (bf16_t*)(p + off); off += (size_t)M_ * 128 * 2;        // 8 MB
  bf16_t* P2TB = (bf16_t*)(p + off); off += (size_t)B_ * S_ * D2_ * 2;   // 4 MB
  bf16_t* W1AT = (bf16_t*)(p + off); off += (size_t)C1_ * 128 * 2;       // 64 KB
  bf16_t* W1BT = (bf16_t*)(p + off); off += (size_t)C1_ * 256 * 2;       // 128 KB
  bf16_t* W2T  = (bf16_t*)(p + off); off += (size_t)C2_ * C1_ * 2;       // 64 KB
  float4* C4   = (float4*)(p + off); off += (size_t)B_ * S_ * 16;        // 128 KB
  float*  G    = (float*)(p + off);  off += (size_t)B_ * S_ * 256 * 4;   // 8 MB
  bf16_t* Y1   = (bf16_t*)(p + off); off += (size_t)M_ * C1_ * 2;        // 16 MB
  float*  KW   = (float*)(p + off);  off += (size_t)M_ * 3 * 4;          // 384 KB
  int*    KI   = (int*)(p + off);    off += (size_t)M_ * 3 * 4;          // 384 KB
  float*  ST1  = (float*)(p + off);  off += 2048;
  float*  ST2  = (float*)(p + off);  off += 1024;
  int*    CNT  = (int*)(p + off);    off += 16;

  hipMemsetAsync(ST1, 0, 2048 + 1024 + 16, stream);   // ST1+ST2+CNT contiguous

  setup_k<<<6688, 256, 0, stream>>>(points2, points1, w1, w2, xyz2,
                                    P2TB, Xp1, W1AT, W1BT, W2T, C4);
  gemmG_k<<<dim3(S_ / 128, 2, B_), 256, 0, stream>>>(P2TB, W1BT, G);
  knn_k<<<1024, 512, 0, stream>>>(xyz1, C4, KW, KI);
  gemm1_k<<<dim3(M_ / 128, 2), 256, 0, stream>>>(Xp1, W1AT, b1, G, KW, KI, Y1, ST1);
  gemm2_k<<<M_ / 128, 256, 0, stream>>>(Y1, W2T, b2, ST1, g1, beta1,
                                        out, ST2, g2, beta2, CNT);
}

// Round 9
// 142.323 us; speedup vs baseline: 10.1353x; 1.2149x over previous
//
#include <hip/hip_runtime.h>

#define B_   2
#define N_   16384
#define S_   4096
#define D1_  128
#define D2_  256
#define C1_  256
#define C2_  128
#define M_   (B_ * N_)   // 32768 rows

typedef __bf16 bf16_t;
typedef bf16_t bf16x8 __attribute__((ext_vector_type(8)));
typedef float  f32x4  __attribute__((ext_vector_type(4)));

// ---------------------------------------------------------------- helpers
__device__ __forceinline__ void gload16(const void* g, void* l) {
  __builtin_amdgcn_global_load_lds(
      (const __attribute__((address_space(1))) void*)g,
      (__attribute__((address_space(3))) void*)l, 16, 0, 0);
}

// top-3 insert; med3 via min/max so compiler emits v_med3_f32
#define INSERT3(v, ix)                                                   \
  {                                                                      \
    bool b0_ = (v) < m0, b1_ = (v) < m1, b2_ = (v) < m2;                 \
    float nm0 = fminf((v), m0);                                          \
    float nm1 = fminf(fmaxf((v), m0), m1);                               \
    float nm2 = fminf(fmaxf((v), m1), m2);                               \
    j2 = b1_ ? j1 : (b2_ ? (ix) : j2);                                   \
    j1 = b0_ ? j0 : (b1_ ? (ix) : j1);                                   \
    j0 = b0_ ? (ix) : j0;                                                \
    m0 = nm0; m1 = nm1; m2 = nm2;                                        \
  }

// ---------------------------------------------------------------- K0: phase1 — knn + points1 transpose + weight prep (heterogeneous blocks)
// blocks [0,1024): brute 3-NN (candidates computed on the fly) -> KW, KI
// blocks [1024,3072): points1 [B][128][16384] -> Xp1 bf16 [M][128]
// blocks [3072,3200): w1at [256][128], w2t [128][256] bf16
union SMem1 {
  struct { float4 cbuf[1024]; float T3V[2][3][32]; int T3I[2][3][32]; } knn;
  float tile[2][32][33];
};

__global__ __launch_bounds__(512, 8) void phase1_k(const float* __restrict__ xyz1,
                                                   const float* __restrict__ xyz2,
                                                   const float* __restrict__ points1,
                                                   const float* __restrict__ w1,
                                                   const float* __restrict__ w2,
                                                   float* __restrict__ kw,
                                                   int* __restrict__ ki,
                                                   bf16_t* __restrict__ Xp1,
                                                   bf16_t* __restrict__ w1at,
                                                   bf16_t* __restrict__ w2t) {
  __shared__ SMem1 sm;
  int bi = blockIdx.x, t = threadIdx.x;
  if (bi < 1024) {
    // ---------------- knn ----------------
    int l = t & 63, w = t >> 6;
    int q = l & 31, h = l >> 5;
    int s = w * 2 + h;                          // slice 0..15
    int b  = bi >> 9;                           // 512 blocks per batch
    int nb = (bi & 511) * 32;
    int n  = nb + q;
    const float* X1 = xyz1 + (size_t)b * 3 * N_;
    const float* X2 = xyz2 + (size_t)b * 3 * S_;
    float ax = X1[n], ay = X1[N_ + n], az = X1[2 * N_ + n];
    float p = ax * ax + ay * ay + az * az;
    float m0 = 3e38f, m1 = 3e38f, m2 = 3e38f;
    int   j0 = 0, j1 = 0, j2 = 0;
    for (int r = 0; r < 4; ++r) {
      __syncthreads();                          // prev round's scan done
      {
        int i0 = r * 1024 + t;
        float x = X2[i0], y = X2[S_ + i0], z = X2[2 * S_ + i0];
        sm.knn.cbuf[t] = make_float4(-2.f * x, -2.f * y, -2.f * z, x * x + y * y + z * z);
        int i1 = i0 + 512;
        x = X2[i1]; y = X2[S_ + i1]; z = X2[2 * S_ + i1];
        sm.knn.cbuf[t + 512] = make_float4(-2.f * x, -2.f * y, -2.f * z, x * x + y * y + z * z);
      }
      __syncthreads();                          // staged data visible
      const float4* cs = sm.knn.cbuf + s * 64;
      int base = r * 1024 + s * 64;
#pragma unroll 8
      for (int i = 0; i < 64; ++i) {
        float4 c = cs[i];
        float v = c.w;
        v = fmaf(az, c.z, v);
        v = fmaf(ay, c.y, v);
        v = fmaf(ax, c.x, v);
        int idx = base + i;
        INSERT3(v, idx);
      }
    }
    __syncthreads();                            // all scans done; reuse cbuf
    float* SV = (float*)sm.knn.cbuf;            // [16][3][32]
    int*   SI = (int*)sm.knn.cbuf + 1536;       // [16][3][32]
    SV[(s * 3 + 0) * 32 + q] = m0;  SV[(s * 3 + 1) * 32 + q] = m1;  SV[(s * 3 + 2) * 32 + q] = m2;
    SI[(s * 3 + 0) * 32 + q] = j0;  SI[(s * 3 + 1) * 32 + q] = j1;  SI[(s * 3 + 2) * 32 + q] = j2;
    __syncthreads();
    if (t < 64) {                               // stage A: merge 8 slices each
      int th = t >> 5, tq = t & 31;
      float m0 = 3e38f, m1 = 3e38f, m2 = 3e38f;
      int j0 = 0, j1 = 0, j2 = 0;
      for (int s2 = th * 8; s2 < th * 8 + 8; ++s2)
#pragma unroll
        for (int k = 0; k < 3; ++k) {
          float v = SV[(s2 * 3 + k) * 32 + tq];
          int  ix = SI[(s2 * 3 + k) * 32 + tq];
          INSERT3(v, ix);
        }
      sm.knn.T3V[th][0][tq] = m0; sm.knn.T3V[th][1][tq] = m1; sm.knn.T3V[th][2][tq] = m2;
      sm.knn.T3I[th][0][tq] = j0; sm.knn.T3I[th][1][tq] = j1; sm.knn.T3I[th][2][tq] = j2;
    }
    __syncthreads();
    if (t < 32) {                               // stage B: final merge; t == own query
      float m0 = sm.knn.T3V[0][0][t], m1 = sm.knn.T3V[0][1][t], m2 = sm.knn.T3V[0][2][t];
      int   j0 = sm.knn.T3I[0][0][t], j1 = sm.knn.T3I[0][1][t], j2 = sm.knn.T3I[0][2][t];
#pragma unroll
      for (int k = 0; k < 3; ++k) {
        float v = sm.knn.T3V[1][k][t];
        int  ix = sm.knn.T3I[1][k][t];
        INSERT3(v, ix);
      }
      float d0 = fmaxf(p + m0, 1e-6f);
      float d1 = fmaxf(p + m1, 1e-6f);
      float d2 = fmaxf(p + m2, 1e-6f);
      float r0 = 1.f / d0, r1 = 1.f / d1, r2 = 1.f / d2;
      float dn = fmaxf(r0 + r1 + r2, 1e-6f);
      size_t rr = (size_t)b * N_ + n;
      kw[rr * 3 + 0] = r0 / dn;  kw[rr * 3 + 1] = r1 / dn;  kw[rr * 3 + 2] = r2 / dn;
      ki[rr * 3 + 0] = j0;       ki[rr * 3 + 1] = j1;       ki[rr * 3 + 2] = j2;
    }
  } else if (bi < 3072) {
    // ---------------- points1 transpose -> Xp1 [M][128] bf16 ----------------
    int bj = bi - 1024;
    int b = bj >> 10, rest = bj & 1023;
    int n0 = (rest & 255) * 64, c0 = (rest >> 8) * 32;
    int tx = t & 31, ty = (t >> 5) & 7, th = t >> 8;   // th: which 32-n subtile
    const float* src = points1 + (size_t)b * D1_ * N_;
#pragma unroll
    for (int k = 0; k < 4; ++k)
      sm.tile[th][ty + k * 8][tx] = src[(size_t)(c0 + ty + k * 8) * N_ + n0 + th * 32 + tx];
    __syncthreads();
#pragma unroll
    for (int k = 0; k < 4; ++k)
      Xp1[(size_t)(b * N_ + n0 + th * 32 + ty + k * 8) * 128 + c0 + tx] =
          (bf16_t)sm.tile[th][tx][ty + k * 8];
  } else {
    // ---------------- weight prep ----------------
    int i = (bi - 3072) * 512 + t;              // 0 .. 65535
    if (i < 32768) {                            // w1at[n][k] = w1[k][n], k<128
      int n = i >> 7, k = i & 127;
      w1at[i] = (bf16_t)w1[(size_t)k * C1_ + n];
    } else {
      int j = i - 32768;                        // w2t[n][k] = w2[k][n]
      int n = j >> 8, k = j & 255;
      w2t[j] = (bf16_t)w2[(size_t)k * C2_ + n];
    }
  }
}

// ---------------------------------------------------------------- K1: G = p2^T @ W1b -> bf16 [B][4096][256], self-staged transposes
__global__ __launch_bounds__(512) void gemmG_k(const float* __restrict__ points2,
                                               const float* __restrict__ w1,
                                               bf16_t* __restrict__ G) {
  const int LDP = 40;                           // padded row (elems); 80B, 16B-aligned
  __shared__ bf16_t As[128 * LDP];              // [s][k]
  __shared__ bf16_t Bs[256 * LDP];              // [n][k]
  int t = threadIdx.x, lane = t & 63, w = t >> 6;
  int wr = w >> 2, wc = w & 3;                  // 2x4 waves -> 128m x 256n
  int bb = blockIdx.x >> 5;
  int m0 = (blockIdx.x & 31) * 128;
  const float* P2 = points2 + (size_t)bb * D2_ * S_;   // [256][4096]
  f32x4 acc[4][4];
  f32x4 z = {0.f, 0.f, 0.f, 0.f};
#pragma unroll
  for (int i = 0; i < 4; ++i)
#pragma unroll
    for (int j = 0; j < 4; ++j) acc[i][j] = z;
  int sA = t & 127, kgA = t >> 7;               // A: 128 s x 32 k, 8 k per thread
  int nB = t & 255, kgB = t >> 8;               // B: 256 n x 32 k, 16 k per thread
  for (int k0 = 0; k0 < 256; k0 += 32) {
    __syncthreads();
    {
      bf16x8 ap;
#pragma unroll
      for (int kk = 0; kk < 8; ++kk)
        ap[kk] = (bf16_t)P2[(size_t)(k0 + kgA * 8 + kk) * S_ + m0 + sA];
      *(bf16x8*)&As[sA * LDP + kgA * 8] = ap;
      bf16x8 bp0, bp1;
#pragma unroll
      for (int kk = 0; kk < 8; ++kk) {
        bp0[kk] = (bf16_t)w1[(size_t)(128 + k0 + kgB * 16 + kk) * C1_ + nB];
        bp1[kk] = (bf16_t)w1[(size_t)(128 + k0 + kgB * 16 + 8 + kk) * C1_ + nB];
      }
      *(bf16x8*)&Bs[nB * LDP + kgB * 16] = bp0;
      *(bf16x8*)&Bs[nB * LDP + kgB * 16 + 8] = bp1;
    }
    __syncthreads();
    bf16x8 af[4], bfr[4];
    int arow = wr * 64 + (lane & 15);
    int brow = wc * 64 + (lane & 15);
    int kc = 8 * (lane >> 4);
#pragma unroll
    for (int i = 0; i < 4; ++i) af[i]  = *(const bf16x8*)&As[(arow + i * 16) * LDP + kc];
#pragma unroll
    for (int j = 0; j < 4; ++j) bfr[j] = *(const bf16x8*)&Bs[(brow + j * 16) * LDP + kc];
#pragma unroll
    for (int i = 0; i < 4; ++i)
#pragma unroll
      for (int j = 0; j < 4; ++j)
        acc[i][j] = __builtin_amdgcn_mfma_f32_16x16x32_bf16(af[i], bfr[j], acc[i][j], 0, 0, 0);
  }
  bf16_t* Gb = G + (size_t)bb * S_ * 256;
#pragma unroll
  for (int j = 0; j < 4; ++j) {
    int col = wc * 64 + j * 16 + (lane & 15);
#pragma unroll
    for (int i = 0; i < 4; ++i) {
      int r = m0 + wr * 64 + i * 16 + ((lane >> 4) << 2);
#pragma unroll
      for (int q = 0; q < 4; ++q)
        Gb[(size_t)(r + q) * 256 + col] = (bf16_t)acc[i][j][q];
    }
  }
}

// ---------------------------------------------------------------- K2: GEMM1 [32768x128]@[128x256] + b1 + Sum w_j G[i_j] -> y1 bf16, BN stats
__global__ __launch_bounds__(256) void gemm1_k(const bf16_t* __restrict__ A,
                                               const bf16_t* __restrict__ Bt,
                                               const float* __restrict__ bias,
                                               const bf16_t* __restrict__ G,
                                               const float* __restrict__ KW,
                                               const int* __restrict__ KI,
                                               bf16_t* __restrict__ Y,
                                               float* __restrict__ st) {
  const int K = 128;
  __shared__ bf16_t As[128 * 32];
  __shared__ bf16_t Bs[128 * 32];
  int tid = threadIdx.x, lane = tid & 63, w = tid >> 6;
  int wr = w >> 1, wc = w & 1;
  int m0 = blockIdx.x * 128, n0 = blockIdx.y * 128;
  int e0 = (w * 2 + 0) * 512 + lane * 8;
  int e1 = (w * 2 + 1) * 512 + lane * 8;
  int ra0 = e0 >> 5, ca0 = e0 & 31;
  int ra1 = e1 >> 5, ca1 = e1 & 31;
  f32x4 acc[4][4];
  f32x4 z = {0.f, 0.f, 0.f, 0.f};
#pragma unroll
  for (int i = 0; i < 4; ++i)
#pragma unroll
    for (int j = 0; j < 4; ++j) acc[i][j] = z;
  for (int k0 = 0; k0 < K; k0 += 32) {
    __syncthreads();
    gload16(A + (size_t)(m0 + ra0) * K + k0 + ca0, &As[e0]);
    gload16(A + (size_t)(m0 + ra1) * K + k0 + ca1, &As[e1]);
    gload16(Bt + (size_t)(n0 + ra0) * K + k0 + ca0, &Bs[e0]);
    gload16(Bt + (size_t)(n0 + ra1) * K + k0 + ca1, &Bs[e1]);
    __syncthreads();
    bf16x8 af[4], bfr[4];
    int arow = wr * 64 + (lane & 15);
    int brow = wc * 64 + (lane & 15);
    int kc = 8 * (lane >> 4);
#pragma unroll
    for (int i = 0; i < 4; ++i) af[i]  = *(const bf16x8*)&As[(arow + i * 16) * 32 + kc];
#pragma unroll
    for (int j = 0; j < 4; ++j) bfr[j] = *(const bf16x8*)&Bs[(brow + j * 16) * 32 + kc];
#pragma unroll
    for (int i = 0; i < 4; ++i)
#pragma unroll
      for (int j = 0; j < 4; ++j)
        acc[i][j] = __builtin_amdgcn_mfma_f32_16x16x32_bf16(af[i], bfr[j], acc[i][j], 0, 0, 0);
  }
  // stage this block's KW/KI into LDS (reuse As)
  __syncthreads();
  float* kwls = (float*)As;                   // 128*3 floats
  int*   kils = ((int*)As) + 384;             // 128*3 ints
  if (tid < 128) {
    int r = m0 + tid;
    kwls[tid * 3 + 0] = KW[(size_t)r * 3 + 0];
    kwls[tid * 3 + 1] = KW[(size_t)r * 3 + 1];
    kwls[tid * 3 + 2] = KW[(size_t)r * 3 + 2];
    kils[tid * 3 + 0] = KI[(size_t)r * 3 + 0];
    kils[tid * 3 + 1] = KI[(size_t)r * 3 + 1];
    kils[tid * 3 + 2] = KI[(size_t)r * 3 + 2];
  }
  __syncthreads();
  int bb = m0 >> 14;
  const bf16_t* Gb = G + (size_t)bb * S_ * 256;
  float sjv[4]  = {0.f, 0.f, 0.f, 0.f};
  float ssjv[4] = {0.f, 0.f, 0.f, 0.f};
#pragma unroll
  for (int i = 0; i < 4; ++i) {
#pragma unroll
    for (int qq = 0; qq < 4; ++qq) {
      int rl = wr * 64 + i * 16 + ((lane >> 4) << 2) + qq;
      float w0 = kwls[rl * 3 + 0], w1v = kwls[rl * 3 + 1], w2v = kwls[rl * 3 + 2];
      const bf16_t* g0 = Gb + (size_t)kils[rl * 3 + 0] * 256;
      const bf16_t* g1 = Gb + (size_t)kils[rl * 3 + 1] * 256;
      const bf16_t* g2 = Gb + (size_t)kils[rl * 3 + 2] * 256;
      int r = m0 + rl;
#pragma unroll
      for (int j = 0; j < 4; ++j) {
        int col = n0 + wc * 64 + j * 16 + (lane & 15);
        float y = acc[i][j][qq] + bias[col]
                + w0 * (float)g0[col] + w1v * (float)g1[col] + w2v * (float)g2[col];
        Y[(size_t)r * C1_ + col] = (bf16_t)y;
        sjv[j] += y;  ssjv[j] += y * y;
      }
    }
  }
#pragma unroll
  for (int j = 0; j < 4; ++j) {
    float sj = sjv[j], ssj = ssjv[j];
    sj  += __shfl_xor(sj, 16);  sj  += __shfl_xor(sj, 32);
    ssj += __shfl_xor(ssj, 16); ssj += __shfl_xor(ssj, 32);
    if ((lane >> 4) == 0) {
      int col = n0 + wc * 64 + j * 16 + (lane & 15);
      atomicAdd(&st[col], sj);
      atomicAdd(&st[C1_ + col], ssj);
    }
  }
}

// ---------------------------------------------------------------- K3: GEMM2 with fused BN1(A-load, prefetched) -> raw y2 transposed + BN2 stats
__global__ __launch_bounds__(256) void gemm2_k(const bf16_t* __restrict__ Y1,
                                               const bf16_t* __restrict__ Bt,
                                               const float* __restrict__ bias,
                                               const float* __restrict__ st1,
                                               const float* __restrict__ g1v,
                                               const float* __restrict__ be1,
                                               float* __restrict__ OUT,
                                               float* __restrict__ st2) {
  const int K = 256;
  __shared__ bf16_t As[128 * 32];
  __shared__ bf16_t Bs[128 * 32];
  __shared__ float sa1[C1_], sb1[C1_];
  int tid = threadIdx.x, lane = tid & 63, w = tid >> 6;
  int wr = w >> 1, wc = w & 1;
  int m0 = blockIdx.x * 128;
  {                                             // BN1 coefficients
    const float invM = 1.f / (float)M_;
    float mu  = st1[tid] * invM;
    float var = fmaxf(st1[C1_ + tid] * invM - mu * mu, 0.f);
    float a = g1v[tid] * rsqrtf(var + 1e-5f);
    sa1[tid] = a;
    sb1[tid] = be1[tid] - mu * a;
  }
  int e0 = (w * 2 + 0) * 512 + lane * 8;
  int e1 = (w * 2 + 1) * 512 + lane * 8;
  int ra0 = e0 >> 5, ca0 = e0 & 31;
  int ra1 = e1 >> 5, ca1 = e1 & 31;
  f32x4 acc[4][4];
  f32x4 z = {0.f, 0.f, 0.f, 0.f};
#pragma unroll
  for (int i = 0; i < 4; ++i)
#pragma unroll
    for (int j = 0; j < 4; ++j) acc[i][j] = z;
  bf16x8 va0 = *(const bf16x8*)&Y1[(size_t)(m0 + ra0) * C1_ + ca0];
  bf16x8 va1 = *(const bf16x8*)&Y1[(size_t)(m0 + ra1) * C1_ + ca1];
  __syncthreads();                              // sa1/sb1 ready
  for (int k0 = 0; k0 < K; k0 += 32) {
    bf16x8 nb0, nb1;
    if (k0 + 32 < K) {                          // 1-deep prefetch
      nb0 = *(const bf16x8*)&Y1[(size_t)(m0 + ra0) * C1_ + k0 + 32 + ca0];
      nb1 = *(const bf16x8*)&Y1[(size_t)(m0 + ra1) * C1_ + k0 + 32 + ca1];
    }
    if (k0) __syncthreads();
    bf16x8 oa0, oa1;
#pragma unroll
    for (int u = 0; u < 8; ++u) {
      float f0 = (float)va0[u];
      float f1 = (float)va1[u];
      f0 = fmaxf(f0 * sa1[k0 + ca0 + u] + sb1[k0 + ca0 + u], 0.f);
      f1 = fmaxf(f1 * sa1[k0 + ca1 + u] + sb1[k0 + ca1 + u], 0.f);
      oa0[u] = (bf16_t)f0;
      oa1[u] = (bf16_t)f1;
    }
    *(bf16x8*)&As[e0] = oa0;
    *(bf16x8*)&As[e1] = oa1;
    gload16(Bt + (size_t)ra0 * K + k0 + ca0, &Bs[e0]);
    gload16(Bt + (size_t)ra1 * K + k0 + ca1, &Bs[e1]);
    __syncthreads();
    bf16x8 af[4], bfr[4];
    int arow = wr * 64 + (lane & 15);
    int brow = wc * 64 + (lane & 15);
    int kc = 8 * (lane >> 4);
#pragma unroll
    for (int i = 0; i < 4; ++i) af[i]  = *(const bf16x8*)&As[(arow + i * 16) * 32 + kc];
#pragma unroll
    for (int j = 0; j < 4; ++j) bfr[j] = *(const bf16x8*)&Bs[(brow + j * 16) * 32 + kc];
#pragma unroll
    for (int i = 0; i < 4; ++i)
#pragma unroll
      for (int j = 0; j < 4; ++j)
        acc[i][j] = __builtin_amdgcn_mfma_f32_16x16x32_bf16(af[i], bfr[j], acc[i][j], 0, 0, 0);
    va0 = nb0; va1 = nb1;
  }
#pragma unroll
  for (int j = 0; j < 4; ++j) {
    int col = wc * 64 + j * 16 + (lane & 15);
    float bv = bias[col];
    float sj = 0.f, ssj = 0.f;
#pragma unroll
    for (int i = 0; i < 4; ++i) {
      int r  = m0 + wr * 64 + i * 16 + ((lane >> 4) << 2);
      int bb = r >> 14, n = r & (N_ - 1);
      f32x4 v = acc[i][j];
#pragma unroll
      for (int q = 0; q < 4; ++q) {
        v[q] += bv;
        sj += v[q]; ssj += v[q] * v[q];
      }
      *(f32x4*)&OUT[((size_t)(bb * C2_ + col)) * N_ + n] = v;
    }
    sj  += __shfl_xor(sj, 16);  sj  += __shfl_xor(sj, 32);
    ssj += __shfl_xor(ssj, 16); ssj += __shfl_xor(ssj, 32);
    if ((lane >> 4) == 0) {
      atomicAdd(&st2[col], sj);
      atomicAdd(&st2[C2_ + col], ssj);
    }
  }
}

// ---------------------------------------------------------------- K4: in-place BN2+ReLU on d_out (BN finalize folded in)
__global__ __launch_bounds__(256) void bn2apply_k(float* __restrict__ OUT,
                                                  const float* __restrict__ st,
                                                  const float* __restrict__ g,
                                                  const float* __restrict__ be) {
  __shared__ float ab[2];
  int t = threadIdx.x;
  int c = (blockIdx.x >> 4) & 127;             // 16 blocks per (b,c) row
  if (t == 0) {
    const float invM = 1.f / (float)M_;
    float mu  = st[c] * invM;
    float var = fmaxf(st[C2_ + c] * invM - mu * mu, 0.f);
    float a = g[c] * rsqrtf(var + 1e-5f);
    ab[0] = a;
    ab[1] = be[c] - mu * a;
  }
  __syncthreads();
  float a = ab[0], s = ab[1];
  size_t i4 = (size_t)blockIdx.x * 256 + t;    // float4 index
  f32x4 v = *(f32x4*)&OUT[i4 * 4];
#pragma unroll
  for (int u = 0; u < 4; ++u) v[u] = fmaxf(a * v[u] + s, 0.f);
  *(f32x4*)&OUT[i4 * 4] = v;
}

// ---------------------------------------------------------------- launch
extern "C" void kernel_launch(void* const* d_in, const int* in_sizes, int n_in,
                              void* d_out, int out_size, void* d_ws, size_t ws_size,
                              hipStream_t stream) {
  const float* xyz1    = (const float*)d_in[0];
  const float* xyz2    = (const float*)d_in[1];
  const float* points1 = (const float*)d_in[2];
  const float* points2 = (const float*)d_in[3];
  const float* w1      = (const float*)d_in[4];
  const float* b1      = (const float*)d_in[5];
  const float* g1      = (const float*)d_in[6];
  const float* beta1   = (const float*)d_in[7];
  const float* w2      = (const float*)d_in[8];
  const float* b2      = (const float*)d_in[9];
  const float* g2      = (const float*)d_in[10];
  const float* beta2   = (const float*)d_in[11];
  float* out = (float*)d_out;

  char* p = (char*)d_ws;
  size_t off = 0;
  bf16_t* Xp1  = (bf16_t*)(p + off); off += (size_t)M_ * 128 * 2;        // 8 MB
  bf16_t* W1AT = (bf16_t*)(p + off); off += (size_t)C1_ * 128 * 2;       // 64 KB
  bf16_t* W2T  = (bf16_t*)(p + off); off += (size_t)C2_ * C1_ * 2;       // 64 KB
  bf16_t* G    = (bf16_t*)(p + off); off += (size_t)B_ * S_ * 256 * 2;   // 4 MB
  bf16_t* Y1   = (bf16_t*)(p + off); off += (size_t)M_ * C1_ * 2;        // 16 MB
  float*  KW   = (float*)(p + off);  off += (size_t)M_ * 3 * 4;          // 384 KB
  int*    KI   = (int*)(p + off);    off += (size_t)M_ * 3 * 4;          // 384 KB
  float*  ST1  = (float*)(p + off);  off += 2048;
  float*  ST2  = (float*)(p + off);  off += 1024;

  hipMemsetAsync(ST1, 0, 3072, stream);   // ST1 + ST2 contiguous

  phase1_k<<<3200, 512, 0, stream>>>(xyz1, xyz2, points1, w1, w2,
                                     KW, KI, Xp1, W1AT, W2T);
  gemmG_k<<<64, 512, 0, stream>>>(points2, w1, G);
  gemm1_k<<<dim3(M_ / 128, 2), 256, 0, stream>>>(Xp1, W1AT, b1, G, KW, KI, Y1, ST1);
  gemm2_k<<<M_ / 128, 256, 0, stream>>>(Y1, W2T, b2, ST1, g1, beta1, out, ST2);
  bn2apply_k<<<4096, 256, 0, stream>>>(out, ST2, g2, beta2);
}

// Round 10
// 135.490 us; speedup vs baseline: 10.6464x; 1.0504x over previous
//
#include <hip/hip_runtime.h>

#define B_   2
#define N_   16384
#define S_   4096
#define D1_  128
#define D2_  256
#define C1_  256
#define C2_  128
#define M_   (B_ * N_)   // 32768 rows

typedef __bf16 bf16_t;
typedef bf16_t bf16x8 __attribute__((ext_vector_type(8)));
typedef float  f32x4  __attribute__((ext_vector_type(4)));

// ---------------------------------------------------------------- helpers
__device__ __forceinline__ void gload16(const void* g, void* l) {
  __builtin_amdgcn_global_load_lds(
      (const __attribute__((address_space(1))) void*)g,
      (__attribute__((address_space(3))) void*)l, 16, 0, 0);
}

// candidate payload: (-2x,-2y,-2z,|c|^2), explicit fmaf tree (pass1==pass2 bitwise)
__device__ __forceinline__ float4 cand4(const float* __restrict__ X2, int i) {
  float x = X2[i], y = X2[S_ + i], z = X2[2 * S_ + i];
  float w = fmaf(x, x, fmaf(y, y, z * z));
  return make_float4(-2.f * x, -2.f * y, -2.f * z, w);
}
__device__ __forceinline__ float distv(float4 c, float ax, float ay, float az) {
  return fmaf(ax, c.x, fmaf(ay, c.y, fmaf(az, c.z, c.w)));
}
// value-only top-3 track: 1 fmin + 2 med3 (fmin(fmax) fuses to v_med3_f32)
#define TRACK3(v)                                                        \
  {                                                                      \
    float t0_ = fminf((v), m0);                                          \
    float t1_ = fminf(fmaxf((v), m0), m1);                               \
    float t2_ = fminf(fmaxf((v), m1), m2);                               \
    m0 = t0_; m1 = t1_; m2 = t2_;                                        \
  }

// ---------------------------------------------------------------- K0: phase1 — knn + points1 transpose + weight prep (heterogeneous blocks)
// blocks [0,1024): two-pass brute 3-NN -> KW, KI
// blocks [1024,3072): points1 [B][128][16384] -> Xp1 bf16 [M][128]
// blocks [3072,3200): w1at [256][128], w2t [128][256] bf16
union SMem1 {
  struct { float4 cbuf[1024]; float T3V[2][3][32]; float QMv[32][3]; } knn;
  float tile[2][32][33];
};

__global__ __launch_bounds__(512, 8) void phase1_k(const float* __restrict__ xyz1,
                                                   const float* __restrict__ xyz2,
                                                   const float* __restrict__ points1,
                                                   const float* __restrict__ w1,
                                                   const float* __restrict__ w2,
                                                   float* __restrict__ kw,
                                                   int* __restrict__ ki,
                                                   bf16_t* __restrict__ Xp1,
                                                   bf16_t* __restrict__ w1at,
                                                   bf16_t* __restrict__ w2t) {
  __shared__ SMem1 sm;
  int bi = blockIdx.x, t = threadIdx.x;
  if (bi < 1024) {
    // ---------------- knn ----------------
    int l = t & 63, w = t >> 6;
    int q = l & 31, h = l >> 5;
    int s = w * 2 + h;                          // slice 0..15
    int b  = bi >> 9;                           // 512 blocks per batch
    int nb = (bi & 511) * 32;
    int n  = nb + q;
    const float* X1 = xyz1 + (size_t)b * 3 * N_;
    const float* X2 = xyz2 + (size_t)b * 3 * S_;
    float ax = X1[n], ay = X1[N_ + n], az = X1[2 * N_ + n];
    float p = fmaf(ax, ax, fmaf(ay, ay, az * az));
    float m0 = 3e38f, m1 = 3e38f, m2 = 3e38f;
    // ============ PASS 1: values only ============
    for (int r = 0; r < 4; ++r) {
      __syncthreads();                          // prev round's scan done
      sm.knn.cbuf[t]       = cand4(X2, r * 1024 + t);
      sm.knn.cbuf[t + 512] = cand4(X2, r * 1024 + t + 512);
      __syncthreads();                          // staged data visible
      const float4* cs = sm.knn.cbuf + s * 64;
#pragma unroll 8
      for (int i = 0; i < 64; ++i) {
        float v = distv(cs[i], ax, ay, az);
        TRACK3(v);
      }
    }
    __syncthreads();                            // scans done; reuse cbuf
    float* SV = (float*)sm.knn.cbuf;            // [16][3][32]
    SV[(s * 3 + 0) * 32 + q] = m0;  SV[(s * 3 + 1) * 32 + q] = m1;  SV[(s * 3 + 2) * 32 + q] = m2;
    __syncthreads();
    if (t < 64) {                               // stage A: value-merge 8 slices each
      int th = t >> 5, tq = t & 31;
      float m0 = 3e38f, m1 = 3e38f, m2 = 3e38f;
      for (int s2 = th * 8; s2 < th * 8 + 8; ++s2)
#pragma unroll
        for (int k = 0; k < 3; ++k) {
          float v = SV[(s2 * 3 + k) * 32 + tq];
          TRACK3(v);
        }
      sm.knn.T3V[th][0][tq] = m0; sm.knn.T3V[th][1][tq] = m1; sm.knn.T3V[th][2][tq] = m2;
    }
    __syncthreads();
    float g0 = 3e38f, g1 = 3e38f, g2 = 3e38f;   // query-global top3 (valid on t<32)
    if (t < 32) {
      float m0 = sm.knn.T3V[0][0][t], m1 = sm.knn.T3V[0][1][t], m2 = sm.knn.T3V[0][2][t];
#pragma unroll
      for (int k = 0; k < 3; ++k) {
        float v = sm.knn.T3V[1][k][t];
        TRACK3(v);
      }
      g0 = m0; g1 = m1; g2 = m2;
      sm.knn.QMv[t][0] = m0; sm.knn.QMv[t][1] = m1; sm.knn.QMv[t][2] = m2;
    }
    __syncthreads();
    float q0v = sm.knn.QMv[q][0], q1v = sm.knn.QMv[q][1], q2v = sm.knn.QMv[q][2];
    // ============ PASS 2: index recovery ============
    unsigned j0 = 0xFFFFFFFFu, j1 = 0xFFFFFFFFu, j2 = 0xFFFFFFFFu;
    for (int r = 0; r < 4; ++r) {
      __syncthreads();
      sm.knn.cbuf[t]       = cand4(X2, r * 1024 + t);
      sm.knn.cbuf[t + 512] = cand4(X2, r * 1024 + t + 512);
      __syncthreads();
      const float4* cs = sm.knn.cbuf + s * 64;
      int base = r * 1024 + s * 64;
#pragma unroll
      for (int g = 0; g < 16; ++g) {            // groups of 4
        float v0 = distv(cs[g * 4 + 0], ax, ay, az);
        float v1 = distv(cs[g * 4 + 1], ax, ay, az);
        float v2 = distv(cs[g * 4 + 2], ax, ay, az);
        float v3 = distv(cs[g * 4 + 3], ax, ay, az);
        float gm = fminf(fminf(v0, v1), fminf(v2, v3));
        if (gm <= q2v) {                        // rare: ~3 hits per query total
#define CHK(vv, uu)                                                      \
          {                                                              \
            unsigned idx = (unsigned)(base + g * 4 + uu);                \
            bool h0 = ((vv) == q0v) && (j0 == 0xFFFFFFFFu);              \
            bool h1 = ((vv) == q1v) && (j1 == 0xFFFFFFFFu) && !h0;       \
            bool h2 = ((vv) == q2v) && (j2 == 0xFFFFFFFFu) && !h0 && !h1;\
            if (h0) j0 = idx;                                            \
            if (h1) j1 = idx;                                            \
            if (h2) j2 = idx;                                            \
          }
          CHK(v0, 0) CHK(v1, 1) CHK(v2, 2) CHK(v3, 3)
#undef CHK
        }
      }
    }
    __syncthreads();                            // scans done; reuse cbuf
    unsigned* SI = (unsigned*)sm.knn.cbuf;      // [16][3][32]
    SI[(s * 3 + 0) * 32 + q] = j0;  SI[(s * 3 + 1) * 32 + q] = j1;  SI[(s * 3 + 2) * 32 + q] = j2;
    __syncthreads();
    if (t < 32) {                               // min-idx reduce (0xFFFFFFFF = none); t == own query
      unsigned a0 = 0xFFFFFFFFu, a1 = 0xFFFFFFFFu, a2 = 0xFFFFFFFFu;
      for (int s2 = 0; s2 < 16; ++s2) {
        a0 = min(a0, SI[(s2 * 3 + 0) * 32 + t]);
        a1 = min(a1, SI[(s2 * 3 + 1) * 32 + t]);
        a2 = min(a2, SI[(s2 * 3 + 2) * 32 + t]);
      }
      a0 = min(a0, (unsigned)(S_ - 1));
      a1 = min(a1, (unsigned)(S_ - 1));
      a2 = min(a2, (unsigned)(S_ - 1));
      float d0 = fmaxf(p + g0, 1e-6f);
      float d1 = fmaxf(p + g1, 1e-6f);
      float d2 = fmaxf(p + g2, 1e-6f);
      float r0 = 1.f / d0, r1 = 1.f / d1, r2 = 1.f / d2;
      float dn = fmaxf(r0 + r1 + r2, 1e-6f);
      size_t rr = (size_t)b * N_ + n;
      kw[rr * 3 + 0] = r0 / dn;  kw[rr * 3 + 1] = r1 / dn;  kw[rr * 3 + 2] = r2 / dn;
      ki[rr * 3 + 0] = (int)a0;  ki[rr * 3 + 1] = (int)a1;  ki[rr * 3 + 2] = (int)a2;
    }
  } else if (bi < 3072) {
    // ---------------- points1 transpose -> Xp1 [M][128] bf16 ----------------
    int bj = bi - 1024;
    int b = bj >> 10, rest = bj & 1023;
    int n0 = (rest & 255) * 64, c0 = (rest >> 8) * 32;
    int tx = t & 31, ty = (t >> 5) & 7, th = t >> 8;   // th: which 32-n subtile
    const float* src = points1 + (size_t)b * D1_ * N_;
#pragma unroll
    for (int k = 0; k < 4; ++k)
      sm.tile[th][ty + k * 8][tx] = src[(size_t)(c0 + ty + k * 8) * N_ + n0 + th * 32 + tx];
    __syncthreads();
#pragma unroll
    for (int k = 0; k < 4; ++k)
      Xp1[(size_t)(b * N_ + n0 + th * 32 + ty + k * 8) * 128 + c0 + tx] =
          (bf16_t)sm.tile[th][tx][ty + k * 8];
  } else {
    // ---------------- weight prep ----------------
    int i = (bi - 3072) * 512 + t;              // 0 .. 65535
    if (i < 32768) {                            // w1at[n][k] = w1[k][n], k<128
      int n = i >> 7, k = i & 127;
      w1at[i] = (bf16_t)w1[(size_t)k * C1_ + n];
    } else {
      int j = i - 32768;                        // w2t[n][k] = w2[k][n]
      int n = j >> 8, k = j & 255;
      w2t[j] = (bf16_t)w2[(size_t)k * C2_ + n];
    }
  }
}

// ---------------------------------------------------------------- K1: G = p2^T @ W1b -> bf16 [B][4096][256], self-staged transposes
__global__ __launch_bounds__(512) void gemmG_k(const float* __restrict__ points2,
                                               const float* __restrict__ w1,
                                               bf16_t* __restrict__ G) {
  const int LDP = 40;                           // padded row (elems); 80B, 16B-aligned
  __shared__ bf16_t As[128 * LDP];              // [s][k]
  __shared__ bf16_t Bs[256 * LDP];              // [n][k]
  int t = threadIdx.x, lane = t & 63, w = t >> 6;
  int wr = w >> 2, wc = w & 3;                  // 2x4 waves -> 128m x 256n
  int bb = blockIdx.x >> 5;
  int m0 = (blockIdx.x & 31) * 128;
  const float* P2 = points2 + (size_t)bb * D2_ * S_;   // [256][4096]
  f32x4 acc[4][4];
  f32x4 z = {0.f, 0.f, 0.f, 0.f};
#pragma unroll
  for (int i = 0; i < 4; ++i)
#pragma unroll
    for (int j = 0; j < 4; ++j) acc[i][j] = z;
  int sA = t & 127, kgA = t >> 7;               // A: 128 s x 32 k, 8 k per thread
  int nB = t & 255, kgB = t >> 8;               // B: 256 n x 32 k, 16 k per thread
  for (int k0 = 0; k0 < 256; k0 += 32) {
    __syncthreads();
    {
      bf16x8 ap;
#pragma unroll
      for (int kk = 0; kk < 8; ++kk)
        ap[kk] = (bf16_t)P2[(size_t)(k0 + kgA * 8 + kk) * S_ + m0 + sA];
      *(bf16x8*)&As[sA * LDP + kgA * 8] = ap;
      bf16x8 bp0, bp1;
#pragma unroll
      for (int kk = 0; kk < 8; ++kk) {
        bp0[kk] = (bf16_t)w1[(size_t)(128 + k0 + kgB * 16 + kk) * C1_ + nB];
        bp1[kk] = (bf16_t)w1[(size_t)(128 + k0 + kgB * 16 + 8 + kk) * C1_ + nB];
      }
      *(bf16x8*)&Bs[nB * LDP + kgB * 16] = bp0;
      *(bf16x8*)&Bs[nB * LDP + kgB * 16 + 8] = bp1;
    }
    __syncthreads();
    bf16x8 af[4], bfr[4];
    int arow = wr * 64 + (lane & 15);
    int brow = wc * 64 + (lane & 15);
    int kc = 8 * (lane >> 4);
#pragma unroll
    for (int i = 0; i < 4; ++i) af[i]  = *(const bf16x8*)&As[(arow + i * 16) * LDP + kc];
#pragma unroll
    for (int j = 0; j < 4; ++j) bfr[j] = *(const bf16x8*)&Bs[(brow + j * 16) * LDP + kc];
#pragma unroll
    for (int i = 0; i < 4; ++i)
#pragma unroll
      for (int j = 0; j < 4; ++j)
        acc[i][j] = __builtin_amdgcn_mfma_f32_16x16x32_bf16(af[i], bfr[j], acc[i][j], 0, 0, 0);
  }
  bf16_t* Gb = G + (size_t)bb * S_ * 256;
#pragma unroll
  for (int j = 0; j < 4; ++j) {
    int col = wc * 64 + j * 16 + (lane & 15);
#pragma unroll
    for (int i = 0; i < 4; ++i) {
      int r = m0 + wr * 64 + i * 16 + ((lane >> 4) << 2);
#pragma unroll
      for (int q = 0; q < 4; ++q)
        Gb[(size_t)(r + q) * 256 + col] = (bf16_t)acc[i][j][q];
    }
  }
}

// ---------------------------------------------------------------- K2: GEMM1 [32768x128]@[128x256] + b1 + Sum w_j G[i_j] -> y1 bf16, BN stats
__global__ __launch_bounds__(256) void gemm1_k(const bf16_t* __restrict__ A,
                                               const bf16_t* __restrict__ Bt,
                                               const float* __restrict__ bias,
                                               const bf16_t* __restrict__ G,
                                               const float* __restrict__ KW,
                                               const int* __restrict__ KI,
                                               bf16_t* __restrict__ Y,
                                               float* __restrict__ st) {
  const int K = 128;
  __shared__ bf16_t As[128 * 32];
  __shared__ bf16_t Bs[128 * 32];
  int tid = threadIdx.x, lane = tid & 63, w = tid >> 6;
  int wr = w >> 1, wc = w & 1;
  int m0 = blockIdx.x * 128, n0 = blockIdx.y * 128;
  int e0 = (w * 2 + 0) * 512 + lane * 8;
  int e1 = (w * 2 + 1) * 512 + lane * 8;
  int ra0 = e0 >> 5, ca0 = e0 & 31;
  int ra1 = e1 >> 5, ca1 = e1 & 31;
  f32x4 acc[4][4];
  f32x4 z = {0.f, 0.f, 0.f, 0.f};
#pragma unroll
  for (int i = 0; i < 4; ++i)
#pragma unroll
    for (int j = 0; j < 4; ++j) acc[i][j] = z;
  for (int k0 = 0; k0 < K; k0 += 32) {
    __syncthreads();
    gload16(A + (size_t)(m0 + ra0) * K + k0 + ca0, &As[e0]);
    gload16(A + (size_t)(m0 + ra1) * K + k0 + ca1, &As[e1]);
    gload16(Bt + (size_t)(n0 + ra0) * K + k0 + ca0, &Bs[e0]);
    gload16(Bt + (size_t)(n0 + ra1) * K + k0 + ca1, &Bs[e1]);
    __syncthreads();
    bf16x8 af[4], bfr[4];
    int arow = wr * 64 + (lane & 15);
    int brow = wc * 64 + (lane & 15);
    int kc = 8 * (lane >> 4);
#pragma unroll
    for (int i = 0; i < 4; ++i) af[i]  = *(const bf16x8*)&As[(arow + i * 16) * 32 + kc];
#pragma unroll
    for (int j = 0; j < 4; ++j) bfr[j] = *(const bf16x8*)&Bs[(brow + j * 16) * 32 + kc];
#pragma unroll
    for (int i = 0; i < 4; ++i)
#pragma unroll
      for (int j = 0; j < 4; ++j)
        acc[i][j] = __builtin_amdgcn_mfma_f32_16x16x32_bf16(af[i], bfr[j], acc[i][j], 0, 0, 0);
  }
  // stage this block's KW/KI into LDS (reuse As)
  __syncthreads();
  float* kwls = (float*)As;                   // 128*3 floats
  int*   kils = ((int*)As) + 384;             // 128*3 ints
  if (tid < 128) {
    int r = m0 + tid;
    kwls[tid * 3 + 0] = KW[(size_t)r * 3 + 0];
    kwls[tid * 3 + 1] = KW[(size_t)r * 3 + 1];
    kwls[tid * 3 + 2] = KW[(size_t)r * 3 + 2];
    kils[tid * 3 + 0] = KI[(size_t)r * 3 + 0];
    kils[tid * 3 + 1] = KI[(size_t)r * 3 + 1];
    kils[tid * 3 + 2] = KI[(size_t)r * 3 + 2];
  }
  __syncthreads();
  int bb = m0 >> 14;
  const bf16_t* Gb = G + (size_t)bb * S_ * 256;
  float sjv[4]  = {0.f, 0.f, 0.f, 0.f};
  float ssjv[4] = {0.f, 0.f, 0.f, 0.f};
#pragma unroll
  for (int i = 0; i < 4; ++i) {
#pragma unroll
    for (int qq = 0; qq < 4; ++qq) {
      int rl = wr * 64 + i * 16 + ((lane >> 4) << 2) + qq;
      float w0 = kwls[rl * 3 + 0], w1v = kwls[rl * 3 + 1], w2v = kwls[rl * 3 + 2];
      const bf16_t* g0 = Gb + (size_t)kils[rl * 3 + 0] * 256;
      const bf16_t* g1 = Gb + (size_t)kils[rl * 3 + 1] * 256;
      const bf16_t* g2 = Gb + (size_t)kils[rl * 3 + 2] * 256;
      int r = m0 + rl;
#pragma unroll
      for (int j = 0; j < 4; ++j) {
        int col = n0 + wc * 64 + j * 16 + (lane & 15);
        float y = acc[i][j][qq] + bias[col]
                + w0 * (float)g0[col] + w1v * (float)g1[col] + w2v * (float)g2[col];
        Y[(size_t)r * C1_ + col] = (bf16_t)y;
        sjv[j] += y;  ssjv[j] += y * y;
      }
    }
  }
#pragma unroll
  for (int j = 0; j < 4; ++j) {
    float sj = sjv[j], ssj = ssjv[j];
    sj  += __shfl_xor(sj, 16);  sj  += __shfl_xor(sj, 32);
    ssj += __shfl_xor(ssj, 16); ssj += __shfl_xor(ssj, 32);
    if ((lane >> 4) == 0) {
      int col = n0 + wc * 64 + j * 16 + (lane & 15);
      atomicAdd(&st[col], sj);
      atomicAdd(&st[C1_ + col], ssj);
    }
  }
}

// ---------------------------------------------------------------- K3: GEMM2 with fused BN1(A-load, prefetched) -> raw y2 transposed + BN2 stats
__global__ __launch_bounds__(256) void gemm2_k(const bf16_t* __restrict__ Y1,
                                               const bf16_t* __restrict__ Bt,
                                               const float* __restrict__ bias,
                                               const float* __restrict__ st1,
                                               const float* __restrict__ g1v,
                                               const float* __restrict__ be1,
                                               float* __restrict__ OUT,
                                               float* __restrict__ st2) {
  const int K = 256;
  __shared__ bf16_t As[128 * 32];
  __shared__ bf16_t Bs[128 * 32];
  __shared__ float sa1[C1_], sb1[C1_];
  int tid = threadIdx.x, lane = tid & 63, w = tid >> 6;
  int wr = w >> 1, wc = w & 1;
  int m0 = blockIdx.x * 128;
  {                                             // BN1 coefficients
    const float invM = 1.f / (float)M_;
    float mu  = st1[tid] * invM;
    float var = fmaxf(st1[C1_ + tid] * invM - mu * mu, 0.f);
    float a = g1v[tid] * rsqrtf(var + 1e-5f);
    sa1[tid] = a;
    sb1[tid] = be1[tid] - mu * a;
  }
  int e0 = (w * 2 + 0) * 512 + lane * 8;
  int e1 = (w * 2 + 1) * 512 + lane * 8;
  int ra0 = e0 >> 5, ca0 = e0 & 31;
  int ra1 = e1 >> 5, ca1 = e1 & 31;
  f32x4 acc[4][4];
  f32x4 z = {0.f, 0.f, 0.f, 0.f};
#pragma unroll
  for (int i = 0; i < 4; ++i)
#pragma unroll
    for (int j = 0; j < 4; ++j) acc[i][j] = z;
  bf16x8 va0 = *(const bf16x8*)&Y1[(size_t)(m0 + ra0) * C1_ + ca0];
  bf16x8 va1 = *(const bf16x8*)&Y1[(size_t)(m0 + ra1) * C1_ + ca1];
  __syncthreads();                              // sa1/sb1 ready
  for (int k0 = 0; k0 < K; k0 += 32) {
    bf16x8 nb0, nb1;
    if (k0 + 32 < K) {                          // 1-deep prefetch
      nb0 = *(const bf16x8*)&Y1[(size_t)(m0 + ra0) * C1_ + k0 + 32 + ca0];
      nb1 = *(const bf16x8*)&Y1[(size_t)(m0 + ra1) * C1_ + k0 + 32 + ca1];
    }
    if (k0) __syncthreads();
    bf16x8 oa0, oa1;
#pragma unroll
    for (int u = 0; u < 8; ++u) {
      float f0 = (float)va0[u];
      float f1 = (float)va1[u];
      f0 = fmaxf(f0 * sa1[k0 + ca0 + u] + sb1[k0 + ca0 + u], 0.f);
      f1 = fmaxf(f1 * sa1[k0 + ca1 + u] + sb1[k0 + ca1 + u], 0.f);
      oa0[u] = (bf16_t)f0;
      oa1[u] = (bf16_t)f1;
    }
    *(bf16x8*)&As[e0] = oa0;
    *(bf16x8*)&As[e1] = oa1;
    gload16(Bt + (size_t)ra0 * K + k0 + ca0, &Bs[e0]);
    gload16(Bt + (size_t)ra1 * K + k0 + ca1, &Bs[e1]);
    __syncthreads();
    bf16x8 af[4], bfr[4];
    int arow = wr * 64 + (lane & 15);
    int brow = wc * 64 + (lane & 15);
    int kc = 8 * (lane >> 4);
#pragma unroll
    for (int i = 0; i < 4; ++i) af[i]  = *(const bf16x8*)&As[(arow + i * 16) * 32 + kc];
#pragma unroll
    for (int j = 0; j < 4; ++j) bfr[j] = *(const bf16x8*)&Bs[(brow + j * 16) * 32 + kc];
#pragma unroll
    for (int i = 0; i < 4; ++i)
#pragma unroll
      for (int j = 0; j < 4; ++j)
        acc[i][j] = __builtin_amdgcn_mfma_f32_16x16x32_bf16(af[i], bfr[j], acc[i][j], 0, 0, 0);
    va0 = nb0; va1 = nb1;
  }
#pragma unroll
  for (int j = 0; j < 4; ++j) {
    int col = wc * 64 + j * 16 + (lane & 15);
    float bv = bias[col];
    float sj = 0.f, ssj = 0.f;
#pragma unroll
    for (int i = 0; i < 4; ++i) {
      int r  = m0 + wr * 64 + i * 16 + ((lane >> 4) << 2);
      int bb = r >> 14, n = r & (N_ - 1);
      f32x4 v = acc[i][j];
#pragma unroll
      for (int q = 0; q < 4; ++q) {
        v[q] += bv;
        sj += v[q]; ssj += v[q] * v[q];
      }
      *(f32x4*)&OUT[((size_t)(bb * C2_ + col)) * N_ + n] = v;
    }
    sj  += __shfl_xor(sj, 16);  sj  += __shfl_xor(sj, 32);
    ssj += __shfl_xor(ssj, 16); ssj += __shfl_xor(ssj, 32);
    if ((lane >> 4) == 0) {
      atomicAdd(&st2[col], sj);
      atomicAdd(&st2[C2_ + col], ssj);
    }
  }
}

// ---------------------------------------------------------------- K4: in-place BN2+ReLU on d_out (BN finalize folded in)
__global__ __launch_bounds__(256) void bn2apply_k(float* __restrict__ OUT,
                                                  const float* __restrict__ st,
                                                  const float* __restrict__ g,
                                                  const float* __restrict__ be) {
  __shared__ float ab[2];
  int t = threadIdx.x;
  int c = (blockIdx.x >> 4) & 127;             // 16 blocks per (b,c) row
  if (t == 0) {
    const float invM = 1.f / (float)M_;
    float mu  = st[c] * invM;
    float var = fmaxf(st[C2_ + c] * invM - mu * mu, 0.f);
    float a = g[c] * rsqrtf(var + 1e-5f);
    ab[0] = a;
    ab[1] = be[c] - mu * a;
  }
  __syncthreads();
  float a = ab[0], s = ab[1];
  size_t i4 = (size_t)blockIdx.x * 256 + t;    // float4 index
  f32x4 v = *(f32x4*)&OUT[i4 * 4];
#pragma unroll
  for (int u = 0; u < 4; ++u) v[u] = fmaxf(a * v[u] + s, 0.f);
  *(f32x4*)&OUT[i4 * 4] = v;
}

// ---------------------------------------------------------------- launch
extern "C" void kernel_launch(void* const* d_in, const int* in_sizes, int n_in,
                              void* d_out, int out_size, void* d_ws, size_t ws_size,
                              hipStream_t stream) {
  const float* xyz1    = (const float*)d_in[0];
  const float* xyz2    = (const float*)d_in[1];
  const float* points1 = (const float*)d_in[2];
  const float* points2 = (const float*)d_in[3];
  const float* w1      = (const float*)d_in[4];
  const float* b1      = (const float*)d_in[5];
  const float* g1      = (const float*)d_in[6];
  const float* beta1   = (const float*)d_in[7];
  const float* w2      = (const float*)d_in[8];
  const float* b2      = (const float*)d_in[9];
  const float* g2      = (const float*)d_in[10];
  const float* beta2   = (const float*)d_in[11];
  float* out = (float*)d_out;

  char* p = (char*)d_ws;
  size_t off = 0;
  bf16_t* Xp1  = (bf16_t*)(p + off); off += (size_t)M_ * 128 * 2;        // 8 MB
  bf16_t* W1AT = (bf16_t*)(p + off); off += (size_t)C1_ * 128 * 2;       // 64 KB
  bf16_t* W2T  = (bf16_t*)(p + off); off += (size_t)C2_ * C1_ * 2;       // 64 KB
  bf16_t* G    = (bf16_t*)(p + off); off += (size_t)B_ * S_ * 256 * 2;   // 4 MB
  bf16_t* Y1   = (bf16_t*)(p + off); off += (size_t)M_ * C1_ * 2;        // 16 MB
  float*  KW   = (float*)(p + off);  off += (size_t)M_ * 3 * 4;          // 384 KB
  int*    KI   = (int*)(p + off);    off += (size_t)M_ * 3 * 4;          // 384 KB
  float*  ST1  = (float*)(p + off);  off += 2048;
  float*  ST2  = (float*)(p + off);  off += 1024;

  hipMemsetAsync(ST1, 0, 3072, stream);   // ST1 + ST2 contiguous

  phase1_k<<<3200, 512, 0, stream>>>(xyz1, xyz2, points1, w1, w2,
                                     KW, KI, Xp1, W1AT, W2T);
  gemmG_k<<<64, 512, 0, stream>>>(points2, w1, G);
  gemm1_k<<<dim3(M_ / 128, 2), 256, 0, stream>>>(Xp1, W1AT, b1, G, KW, KI, Y1, ST1);
  gemm2_k<<<M_ / 128, 256, 0, stream>>>(Y1, W2T, b2, ST1, g1, beta1, out, ST2);
  bn2apply_k<<<4096, 256, 0, stream>>>(out, ST2, g2, beta2);
}